// Round 8
// baseline (410.870 us; speedup 1.0000x reference)
//
#include <hip/hip_runtime.h>
#include <hip/hip_bf16.h>

#define Bsz 4
#define Tt 2048
#define Ll 4096
#define NC 256     // chunks for scan (2048 blocks/dispatch batched over dirs)
#define CH 16      // steps per chunk (NC*CH == Ll)
#define NG 16      // chunk groups for hierarchical combine (NC/NG = 16 chunks/group)

typedef short bf16x8 __attribute__((ext_vector_type(8)));
typedef float f32x4 __attribute__((ext_vector_type(4)));
typedef float f32x2 __attribute__((ext_vector_type(2)));

// Forced VOP3P packed fp32 (compiler may scalarize <2 x float> otherwise).
static __device__ __forceinline__ f32x2 pk_fma(f32x2 a, f32x2 b, f32x2 c){
  f32x2 d;
  asm("v_pk_fma_f32 %0, %1, %2, %3" : "=v"(d) : "v"(a), "v"(b), "v"(c));
  return d;
}
static __device__ __forceinline__ f32x2 pk_mul(f32x2 a, f32x2 b){
  f32x2 d;
  asm("v_pk_mul_f32 %0, %1, %2" : "=v"(d) : "v"(a), "v"(b));
  return d;
}
static __device__ __forceinline__ f32x2 lo2(f32x4 v){ return (f32x2){v.x, v.y}; }
static __device__ __forceinline__ f32x2 hi2(f32x4 v){ return (f32x2){v.z, v.w}; }

static __device__ __forceinline__ float bs2f(unsigned short u){
  union{float f; unsigned int i;} v; v.i = ((unsigned int)u)<<16; return v.f;
}
static __device__ __forceinline__ unsigned short f2bs(float f){
  union{float f; unsigned int i;} v; v.f = f;
  unsigned int r = (v.i + 0x7fffu + ((v.i>>16)&1u)) >> 16;
  return (unsigned short)r;
}

// gate two packed bf16 y-values by silu of two packed bf16 z-values
static __device__ __forceinline__ unsigned int gate2(unsigned int yy, unsigned int zz){
  float y0 = bs2f((unsigned short)(yy & 0xffffu));
  float y1 = bs2f((unsigned short)(yy >> 16));
  float z0 = bs2f((unsigned short)(zz & 0xffffu));
  float z1 = bs2f((unsigned short)(zz >> 16));
  float g0 = z0*__builtin_amdgcn_rcpf(1.f+__expf(-z0));
  float g1 = z1*__builtin_amdgcn_rcpf(1.f+__expf(-z1));
  return (unsigned int)f2bs(y0*g0) | ((unsigned int)f2bs(y1*g1) << 16);
}

// fp32 -> bf16 bulk convert, two source/dest pairs in one dispatch
__global__ void k_cvt2(const float* __restrict__ a, const float* __restrict__ b,
                       unsigned short* __restrict__ da, unsigned short* __restrict__ db,
                       int na, int nb){
  int i = blockIdx.x*256 + threadIdx.x;
  if (i < na) da[i] = f2bs(a[i]);
  else {
    int j = i - na;
    if (j < nb) db[j] = f2bs(b[j]);
  }
}

// pad xproj_w (4 branches, 40x256) to zero-filled 64x256 bf16
__global__ void k_prepx(const float* __restrict__ xw, unsigned short* __restrict__ wxb){
  int row = blockIdx.x, br = blockIdx.y, col = threadIdx.x;
  float v = (row < 40) ? xw[((size_t)br*40 + row)*256 + col] : 0.f;
  wxb[((size_t)br*64 + row)*256 + col] = f2bs(v);
}

// Precompute AEX = -exp(A_log) (4 branches x 4096), per-(br,d) A0 + chain flag.
__global__ void k_prepA(const float* __restrict__ Alog, float* __restrict__ AEX,
                        float* __restrict__ A0C, float* __restrict__ CHN){
  int br = blockIdx.x, d = threadIdx.x;
  float A[16];
  #pragma unroll
  for (int j=0;j<4;j++){
    float4 a4 = *(const float4*)&Alog[(size_t)br*4096 + d*16 + j*4];
    A[4*j]  = -__expf(a4.x); A[4*j+1] = -__expf(a4.y);
    A[4*j+2]= -__expf(a4.z); A[4*j+3] = -__expf(a4.w);
    *(float4*)&AEX[(size_t)br*4096 + d*16 + j*4] = (float4){A[4*j],A[4*j+1],A[4*j+2],A[4*j+3]};
  }
  bool chain = true;
  #pragma unroll
  for (int n=1;n<16;n++){
    float expect = A[0]*(float)(n+1);
    if (fabsf(A[n]-expect) > 1e-3f*fabsf(expect)) chain = false;
  }
  A0C[br*256 + d] = A[0];
  CHN[br*256 + d] = chain ? 1.f : 0.f;
}

// ---------------------------------------------------------------------------
// Compose upsample-conv weights with fuse matmul; emit bf16 GEMM-ready layouts.
// ---------------------------------------------------------------------------
__global__ void k_compose(const float* __restrict__ up_w, const float* __restrict__ fus_w,
                          const float* __restrict__ fus_b, const float* __restrict__ up_b,
                          unsigned short* __restrict__ WEb, unsigned short* __restrict__ WOb,
                          unsigned short* __restrict__ FWSb, float* __restrict__ BIAS2){
  int i = blockIdx.x;     // 0..255
  int o = threadIdx.x;    // 0..127
  float a0=0.f,a1=0.f,a2=0.f,a3=0.f,a4=0.f;
  for (int c=0;c<256;c++){
    float f = fus_w[o*384+c];
    const float* w = up_w + ((size_t)i*256+c)*5;
    a0 += f*w[0]; a1 += f*w[1]; a2 += f*w[2];
    a3 += f*w[3]; a4 += f*w[4];
  }
  WEb[(size_t)o*768 +       i] = f2bs(a4);
  WEb[(size_t)o*768 + 256 + i] = f2bs(a2);
  WEb[(size_t)o*768 + 512 + i] = f2bs(a0);
  WOb[(size_t)o*512 +       i] = f2bs(a3);
  WOb[(size_t)o*512 + 256 + i] = f2bs(a1);
  if (i<128) FWSb[o*128 + i] = f2bs(fus_w[o*384+256+i]);
  if (i==0){
    float bb = fus_b[o];
    for (int c=0;c<256;c++) bb += fus_w[o*384+c]*up_b[c];
    BIAS2[o]=bb;
  }
}

// transpose x (B,256,T) f32 -> XT (B, T+2, 256) bf16, row t stored at t+1.
// Halo rows (t=-1 and t=2048) zeroed by the (0,0,b) blocks.
__global__ __launch_bounds__(256) void k_tx(const float* __restrict__ x, unsigned short* __restrict__ XT){
  __shared__ float tile[64][65];
  int b=blockIdx.z, t0=blockIdx.x*64, i0=blockIdx.y*64;
  int tid=threadIdx.x;
  if (blockIdx.x==0 && blockIdx.y==0){
    XT[((size_t)b*2050)*256 + tid] = 0;
    XT[((size_t)b*2050+2049)*256 + tid] = 0;
  }
  for (int it=0;it<16;it++){
    int idx=it*256+tid; int ii=idx>>6, tt=idx&63;
    tile[ii][tt] = x[((size_t)b*256+i0+ii)*Tt + t0+tt];
  }
  __syncthreads();
  for (int it=0;it<16;it++){
    int idx=it*256+tid; int tt=idx>>6, ii=idx&63;
    XT[((size_t)b*2050 + t0+tt+1)*256 + i0+ii] = f2bs(tile[ii][tt]);
  }
}

// transpose skip (B,128,L) f32 -> SKT (B,L,128) bf16
__global__ __launch_bounds__(256) void k_ts(const float* __restrict__ skip, unsigned short* __restrict__ SKT){
  __shared__ float tile[64][65];
  int b=blockIdx.z, l0=blockIdx.x*64, s0=blockIdx.y*64;
  int tid=threadIdx.x;
  for (int it=0;it<16;it++){
    int idx=it*256+tid; int ss=idx>>6, ll=idx&63;
    tile[ss][ll] = skip[((size_t)b*128+s0+ss)*Ll + l0+ll];
  }
  __syncthreads();
  for (int it=0;it<16;it++){
    int idx=it*256+tid; int ll=idx>>6, ss=idx&63;
    SKT[((size_t)b*Ll + l0+ll)*128 + s0+ss] = f2bs(tile[ss][ll]);
  }
}

// ---------------------------------------------------------------------------
// MFMA upsample+fuse. Block = 64 t x 128 o, one parity.
// ---------------------------------------------------------------------------
__global__ __launch_bounds__(256) void k_up(const unsigned short* __restrict__ XT,
                     const unsigned short* __restrict__ SKT,
                     const unsigned short* __restrict__ WEb, const unsigned short* __restrict__ WOb,
                     const unsigned short* __restrict__ FWSb, const float* __restrict__ B2,
                     float* __restrict__ h0, float* __restrict__ gst){
  __shared__ unsigned short XL[66*264];
  __shared__ unsigned short Wb[128*72];
  __shared__ float red0[256], red1[256];
  int bt = blockIdx.x, par = blockIdx.y, b = blockIdx.z;
  int t0 = bt*64;
  int tid = threadIdx.x;
  int wave = tid>>6, lane = tid&63;
  int wm = wave>>1, wn = wave&1;
  int quad = lane>>4, l16 = lane&15;

  for (int idx=tid; idx<66*32; idx+=256){
    int row = idx>>5, c8 = idx&31;
    *(uint4*)&XL[row*264 + c8*8] = *(const uint4*)&XT[((size_t)b*2050 + t0 + row)*256 + c8*8];
  }

  const unsigned short* Wsrc = par ? WOb : WEb;
  const int Kw = par ? 512 : 768;
  const int tapbase = par ? 1 : 0;
  f32x4 acc[2][4];
  #pragma unroll
  for (int i=0;i<2;i++)
    #pragma unroll
    for (int j=0;j<4;j++) acc[i][j] = (f32x4){0.f,0.f,0.f,0.f};

  int nch = Kw>>6;
  for (int kc=0; kc<nch; kc++){
    __syncthreads();
    #pragma unroll
    for (int it=0; it<4; it++){
      int idx = it*256+tid;
      int row = idx>>3, c8 = idx&7;
      *(uint4*)&Wb[row*72 + c8*8] = *(const uint4*)&Wsrc[(size_t)row*Kw + kc*64 + c8*8];
    }
    __syncthreads();
    #pragma unroll
    for (int ks=0; ks<64; ks+=32){
      int kg = kc*64 + ks;
      int tap = kg>>8, ib = kg&255;
      bf16x8 af[2], bf[4];
      #pragma unroll
      for (int mt=0;mt<2;mt++)
        af[mt] = *(bf16x8*)&XL[(wm*32+mt*16+l16 + tapbase + tap)*264 + ib + quad*8];
      #pragma unroll
      for (int nt=0;nt<4;nt++)
        bf[nt] = *(bf16x8*)&Wb[(wn*64+nt*16+l16)*72 + ks + quad*8];
      #pragma unroll
      for (int mt=0;mt<2;mt++)
        #pragma unroll
        for (int nt=0;nt<4;nt++)
          acc[mt][nt] = __builtin_amdgcn_mfma_f32_16x16x32_bf16(af[mt], bf[nt], acc[mt][nt], 0,0,0);
    }
  }

  __syncthreads();
  for (int idx=tid; idx<64*16; idx+=256){
    int row = idx>>4, c8 = idx&15;
    *(uint4*)&XL[row*136 + c8*8] = *(const uint4*)&SKT[((size_t)b*Ll + 2*(t0+row)+par)*128 + c8*8];
  }
  for (int kc=0; kc<2; kc++){
    __syncthreads();
    #pragma unroll
    for (int it=0; it<4; it++){
      int idx = it*256+tid;
      int row = idx>>3, c8 = idx&7;
      *(uint4*)&Wb[row*72 + c8*8] = *(const uint4*)&FWSb[(size_t)row*128 + kc*64 + c8*8];
    }
    __syncthreads();
    #pragma unroll
    for (int ks=0; ks<64; ks+=32){
      bf16x8 af[2], bf[4];
      #pragma unroll
      for (int mt=0;mt<2;mt++)
        af[mt] = *(bf16x8*)&XL[(wm*32+mt*16+l16)*136 + kc*64 + ks + quad*8];
      #pragma unroll
      for (int nt=0;nt<4;nt++)
        bf[nt] = *(bf16x8*)&Wb[(wn*64+nt*16+l16)*72 + ks + quad*8];
      #pragma unroll
      for (int mt=0;mt<2;mt++)
        #pragma unroll
        for (int nt=0;nt<4;nt++)
          acc[mt][nt] = __builtin_amdgcn_mfma_f32_16x16x32_bf16(af[mt], bf[nt], acc[mt][nt], 0,0,0);
    }
  }

  float s1=0.f, s2=0.f;
  #pragma unroll
  for (int mt=0;mt<2;mt++)
    #pragma unroll
    for (int nt=0;nt<4;nt++)
      #pragma unroll
      for (int r=0;r<4;r++){
        int m = wm*32 + mt*16 + quad*4 + r;
        int lrow = 2*(t0+m) + par;
        int col = wn*64 + nt*16 + l16;
        float v = acc[mt][nt][r] + B2[col];
        h0[((size_t)b*Ll + lrow)*128 + col] = v;
        s1 += v; s2 += v*v;
      }
  red0[tid]=s1; red1[tid]=s2;
  __syncthreads();
  for (int st=128; st>0; st>>=1){
    if (tid<st){ red0[tid]+=red0[tid+st]; red1[tid]+=red1[tid+st]; }
    __syncthreads();
  }
  if (tid==0){ atomicAdd(&gst[b*2], red0[0]); atomicAdd(&gst[b*2+1], red1[0]); }
}

// Fused GroupNorm-apply + PReLU + layer-0 LayerNorm (stats from raw sums).
__global__ __launch_bounds__(256) void k_gnln(const float* __restrict__ h0, const float* __restrict__ gn_w,
                      const float* __restrict__ gn_b, const float* __restrict__ pa,
                      const float* __restrict__ gst, const float* __restrict__ lnw,
                      const float* __restrict__ lnb, float* __restrict__ hres,
                      unsigned short* __restrict__ xn){
  int row = blockIdx.x*4 + (threadIdx.x>>6);
  int lane = threadIdx.x & 63;
  int b = row >> 12;
  const float ninv = 1.f/((float)Ll*128.f);
  float mu_g = gst[b*2]*ninv;
  float var_g = gst[b*2+1]*ninv - mu_g*mu_g;
  float inv_g = rsqrtf(var_g + 1e-5f);
  float a = pa[0];
  const float* hp = h0 + (size_t)row*128;
  float u0 = (hp[lane]   -mu_g)*inv_g*gn_w[lane]    + gn_b[lane];
  float u1 = (hp[lane+64]-mu_g)*inv_g*gn_w[lane+64] + gn_b[lane+64];
  float v0 = u0>=0.f ? u0 : a*u0;
  float v1 = u1>=0.f ? u1 : a*u1;
  float* rp = hres + (size_t)row*128;
  rp[lane] = v0; rp[lane+64] = v1;
  float s = v0+v1, q = v0*v0+v1*v1;
  #pragma unroll
  for (int off=32; off>0; off>>=1){
    s += __shfl_xor(s, off, 64);
    q += __shfl_xor(q, off, 64);
  }
  float mu = s*(1.f/128.f);
  float rs = rsqrtf(q*(1.f/128.f)-mu*mu + 1e-5f);
  unsigned short* xp = xn + (size_t)row*128;
  xp[lane]    = f2bs((v0-mu)*rs*lnw[lane]    + lnb[lane]);
  xp[lane+64] = f2bs((v1-mu)*rs*lnw[lane+64] + lnb[lane+64]);
}

// ---------------------------------------------------------------------------
// MFMA GEMM in_proj, batched over dirs (blockIdx.z): XZ2[dir] = rev_dir(XN) @ W_dir^T
// ---------------------------------------------------------------------------
__global__ __launch_bounds__(256) void k_gemm_in(const unsigned short* __restrict__ A,
                          const unsigned short* __restrict__ W,
                          unsigned short* __restrict__ C){
  __shared__ unsigned short As[128*72];
  __shared__ unsigned short Bs[128*72];
  int tid = threadIdx.x;
  int row0 = blockIdx.x*128;
  int n0   = blockIdx.y*128;
  int dir  = blockIdx.z;
  const unsigned short* Wp = W + (size_t)dir*512*128;
  unsigned short* Cp = C + (size_t)dir*Bsz*Ll*512;
  int wave = tid>>6, lane = tid&63;
  int wm = wave>>1, wn = wave&1;
  int quad = lane>>4, l16 = lane&15;
  f32x4 acc[4][4];
  #pragma unroll
  for (int i=0;i<4;i++)
    #pragma unroll
    for (int j=0;j<4;j++) acc[i][j] = (f32x4){0.f,0.f,0.f,0.f};

  for (int kb=0; kb<128; kb+=64){
    __syncthreads();
    #pragma unroll
    for (int it=0; it<4; it++){
      int idx = it*256 + tid;
      int row = idx>>3, c8 = idx&7;
      int r = row0 + row;
      int p = r & (Ll-1); int bb = r >> 12;
      int src = (bb<<12) + (dir ? (Ll-1-p) : p);
      *(uint4*)&As[row*72 + c8*8] = *(const uint4*)&A[(size_t)src*128 + kb + c8*8];
      *(uint4*)&Bs[row*72 + c8*8] = *(const uint4*)&Wp[(size_t)(n0+row)*128 + kb + c8*8];
    }
    __syncthreads();
    #pragma unroll
    for (int ks=0; ks<64; ks+=32){
      bf16x8 af[4], bf[4];
      #pragma unroll
      for (int mt=0;mt<4;mt++)
        af[mt] = *(bf16x8*)&As[(wm*64+mt*16+l16)*72 + ks + quad*8];
      #pragma unroll
      for (int nt=0;nt<4;nt++)
        bf[nt] = *(bf16x8*)&Bs[(wn*64+nt*16+l16)*72 + ks + quad*8];
      #pragma unroll
      for (int mt=0;mt<4;mt++)
        #pragma unroll
        for (int nt=0;nt<4;nt++)
          acc[mt][nt] = __builtin_amdgcn_mfma_f32_16x16x32_bf16(af[mt], bf[nt], acc[mt][nt], 0,0,0);
    }
  }
  #pragma unroll
  for (int mt=0;mt<4;mt++)
    #pragma unroll
    for (int nt=0;nt<4;nt++)
      #pragma unroll
      for (int r=0;r<4;r++){
        int row = row0 + wm*64 + mt*16 + quad*4 + r;
        int col = n0 + wn*64 + nt*16 + l16;
        Cp[(size_t)row*512 + col] = f2bs(acc[mt][nt][r]);
      }
}

// ---------------------------------------------------------------------------
// Combined out_proj: HR[l] += Y0g[l]@W0^T + Y1g[rev l]@W1^T  (K=512, both dirs)
// Y holds the RAW scan output; gating y*silu(z) applied during A-staging
// (z from the xz plane's second half). DO_LN=1: LayerNorm rows -> bf16 xn.
// ---------------------------------------------------------------------------
template<int DO_LN>
__global__ __launch_bounds__(256) void k_gemm_out_t(const unsigned short* __restrict__ Y,
                           const unsigned short* __restrict__ XZ,
                           const unsigned short* __restrict__ W,
                           float* __restrict__ C, const float* __restrict__ lnw,
                           const float* __restrict__ lnb, unsigned short* __restrict__ xn){
  __shared__ unsigned short As[64*72];
  __shared__ unsigned short Bs[128*72];
  __shared__ float redS[2][4][2][4][2][2];   // [wm][quad][mt][r][wn][{s,q}]
  int tid = threadIdx.x;
  int row0 = blockIdx.x*64;
  int wave = tid>>6, lane = tid&63;
  int wm = wave>>1, wn = wave&1;
  int quad = lane>>4, l16 = lane&15;
  const size_t planeY = (size_t)Bsz*Ll*256;
  const size_t planeXZ = (size_t)Bsz*Ll*512;
  f32x4 acc[2][4];
  #pragma unroll
  for (int i=0;i<2;i++)
    #pragma unroll
    for (int j=0;j<4;j++) acc[i][j] = (f32x4){0.f,0.f,0.f,0.f};

  for (int kc=0; kc<8; kc++){
    int dirp = kc>>2;
    int kb = (kc&3)*64;
    const unsigned short* Wp = W + (size_t)dirp*128*256;
    __syncthreads();
    #pragma unroll
    for (int it=0; it<2; it++){
      int idx = it*256 + tid;
      int row = idx>>3, c8 = idx&7;
      int r = row0 + row;
      int p = r & (Ll-1); int bb = r >> 12;
      int srow = dirp ? ((bb<<12) + (Ll-1-p)) : r;
      uint4 y8 = *(const uint4*)&Y[dirp*planeY + (size_t)srow*256 + kb + c8*8];
      uint4 z8 = *(const uint4*)&XZ[dirp*planeXZ + (size_t)srow*512 + 256 + kb + c8*8];
      uint4 o;
      o.x = gate2(y8.x, z8.x); o.y = gate2(y8.y, z8.y);
      o.z = gate2(y8.z, z8.z); o.w = gate2(y8.w, z8.w);
      *(uint4*)&As[row*72 + c8*8] = o;
    }
    #pragma unroll
    for (int it=0; it<4; it++){
      int idx = it*256 + tid;
      int row = idx>>3, c8 = idx&7;
      *(uint4*)&Bs[row*72 + c8*8] = *(const uint4*)&Wp[(size_t)row*256 + kb + c8*8];
    }
    __syncthreads();
    #pragma unroll
    for (int ks=0; ks<64; ks+=32){
      bf16x8 af[2], bf[4];
      #pragma unroll
      for (int mt=0;mt<2;mt++)
        af[mt] = *(bf16x8*)&As[(wm*32+mt*16+l16)*72 + ks + quad*8];
      #pragma unroll
      for (int nt=0;nt<4;nt++)
        bf[nt] = *(bf16x8*)&Bs[(wn*64+nt*16+l16)*72 + ks + quad*8];
      #pragma unroll
      for (int mt=0;mt<2;mt++)
        #pragma unroll
        for (int nt=0;nt<4;nt++)
          acc[mt][nt] = __builtin_amdgcn_mfma_f32_16x16x32_bf16(af[mt], bf[nt], acc[mt][nt], 0,0,0);
    }
  }

  // epilogue: C += acc (keep final values in regs for LN)
  float vals[2][4][4];
  #pragma unroll
  for (int mt=0;mt<2;mt++)
    #pragma unroll
    for (int nt=0;nt<4;nt++)
      #pragma unroll
      for (int r=0;r<4;r++){
        int row = row0 + wm*32 + mt*16 + quad*4 + r;
        int col = wn*64 + nt*16 + l16;
        float v = C[(size_t)row*128 + col] + acc[mt][nt][r];
        C[(size_t)row*128 + col] = v;
        vals[mt][nt][r] = v;
      }

  if (DO_LN){
    // per-(mt,r) partial sums over this thread's 4 cols, then 16-lane reduce
    #pragma unroll
    for (int mt=0;mt<2;mt++)
      #pragma unroll
      for (int r=0;r<4;r++){
        float s = 0.f, q = 0.f;
        #pragma unroll
        for (int nt=0;nt<4;nt++){ float v = vals[mt][nt][r]; s += v; q += v*v; }
        #pragma unroll
        for (int off=1; off<16; off<<=1){
          s += __shfl_xor(s, off, 64);
          q += __shfl_xor(q, off, 64);
        }
        if (l16 == 0){
          redS[wm][quad][mt][r][wn][0] = s;
          redS[wm][quad][mt][r][wn][1] = q;
        }
      }
    __syncthreads();
    #pragma unroll
    for (int mt=0;mt<2;mt++)
      #pragma unroll
      for (int r=0;r<4;r++){
        float s = redS[wm][quad][mt][r][0][0] + redS[wm][quad][mt][r][1][0];
        float q = redS[wm][quad][mt][r][0][1] + redS[wm][quad][mt][r][1][1];
        float mu = s*(1.f/128.f);
        float rs = rsqrtf(q*(1.f/128.f) - mu*mu + 1e-5f);
        int row = row0 + wm*32 + mt*16 + quad*4 + r;
        #pragma unroll
        for (int nt=0;nt<4;nt++){
          int col = wn*64 + nt*16 + l16;
          xn[(size_t)row*128 + col] = f2bs((vals[mt][nt][r]-mu)*rs*lnw[col] + lnb[col]);
        }
      }
  }
}

// ---------------------------------------------------------------------------
// Fused depthwise conv (K=4, sliding window) + SiLU + MFMA x_proj.
// ---------------------------------------------------------------------------
__global__ __launch_bounds__(256) void k_xproj3(const unsigned short* __restrict__ xz,
                        const unsigned short* __restrict__ wxb,
                        const float* __restrict__ cw, const float* __restrict__ cb,
                        unsigned short* __restrict__ xib, float* __restrict__ dbl){
  __shared__ unsigned short xiS[64*264];
  __shared__ unsigned short Bs[64*72];
  int tid = threadIdx.x;
  int dir = blockIdx.y;
  xz  += (size_t)dir*Bsz*Ll*512;
  wxb += (size_t)dir*64*256;
  cw  += dir*1024;
  cb  += dir*256;
  xib += (size_t)dir*Bsz*Ll*256;
  dbl += (size_t)dir*Bsz*Ll*40;
  size_t row0 = (size_t)blockIdx.x*64;
  int p0 = (int)(row0 & (Ll-1));

  {
    int d = tid;
    float4 w4 = *(const float4*)&cw[d*4];
    float bias = cb[d];
    float w0, w1, w2;
    if (p0 == 0){ w0=0.f; w1=0.f; w2=0.f; }
    else {
      w0 = bs2f(xz[(row0-3)*512 + d]);
      w1 = bs2f(xz[(row0-2)*512 + d]);
      w2 = bs2f(xz[(row0-1)*512 + d]);
    }
    #pragma unroll 4
    for (int rr=0; rr<64; rr++){
      float xv = bs2f(xz[(row0+rr)*512 + d]);
      float acc = bias + w4.x*w0 + w4.y*w1 + w4.z*w2 + w4.w*xv;
      float v = acc*__builtin_amdgcn_rcpf(1.f+__expf(-acc));
      unsigned short us = f2bs(v);
      xiS[rr*264 + d] = us;
      xib[(row0+rr)*256 + d] = us;
      w0=w1; w1=w2; w2=xv;
    }
  }

  int wave = tid>>6, lane = tid&63;
  int quad = lane>>4, l16 = lane&15;
  f32x4 acc[4];
  #pragma unroll
  for (int j=0;j<4;j++) acc[j] = (f32x4){0.f,0.f,0.f,0.f};

  for (int kb=0; kb<256; kb+=64){
    __syncthreads();
    #pragma unroll
    for (int it=0; it<2; it++){
      int idx = it*256 + tid;
      int row = idx>>3, c8 = idx&7;
      *(uint4*)&Bs[row*72 + c8*8] = *(const uint4*)&wxb[(size_t)row*256 + kb + c8*8];
    }
    __syncthreads();
    #pragma unroll
    for (int ks=0; ks<64; ks+=32){
      bf16x8 af = *(bf16x8*)&xiS[(wave*16+l16)*264 + kb + ks + quad*8];
      #pragma unroll
      for (int nt=0;nt<4;nt++){
        bf16x8 bf = *(bf16x8*)&Bs[(nt*16+l16)*72 + ks + quad*8];
        acc[nt] = __builtin_amdgcn_mfma_f32_16x16x32_bf16(af, bf, acc[nt], 0,0,0);
      }
    }
  }
  #pragma unroll
  for (int nt=0;nt<4;nt++)
    #pragma unroll
    for (int r=0;r<4;r++){
      int m = wave*16 + quad*4 + r;
      int col = nt*16 + l16;
      if (col < 40) dbl[(row0+m)*40 + col] = acc[nt][r];
    }
}

// Packed pw2[i] = {e1^(2i+1), e1^(2i+2)}: 1 scalar mul + 7 packed muls (forced VOP3P).
#define POWTREE2(e1, pw2) { \
  float _e2 = (e1)*(e1); \
  f32x2 _e2v = (f32x2){_e2,_e2}; \
  pw2[0] = (f32x2){(e1),_e2}; \
  pw2[1] = pk_mul(pw2[0], _e2v); \
  pw2[2] = pk_mul(pw2[1], _e2v); \
  pw2[3] = pk_mul(pw2[2], _e2v); \
  f32x2 _e8v = (f32x2){pw2[3].y, pw2[3].y}; \
  pw2[4] = pk_mul(pw2[0], _e8v); \
  pw2[5] = pk_mul(pw2[1], _e8v); \
  pw2[6] = pk_mul(pw2[2], _e8v); \
  pw2[7] = pk_mul(pw2[3], _e8v); }

// ---------------------------------------------------------------------------
// Phase 1: chunk-local scan. Emits per-chunk sdt (chunk decay = exp(A[n]*sdt),
// exact) + chunk-end local states Q. Chain path: fully unrolled, packed fp32,
// rcp-softplus (A0==-1).
// ---------------------------------------------------------------------------
__global__ __launch_bounds__(256) void k_scan1(const float* __restrict__ dbl,
                       const unsigned short* __restrict__ xib, const float* __restrict__ AEX,
                       const float* __restrict__ A0C, const float* __restrict__ CHNf,
                       const float* __restrict__ dtw, const float* __restrict__ dtb,
                       float* __restrict__ SD, float* __restrict__ Q){
  __shared__ float dblS[CH*24];
  int b = blockIdx.y, c = blockIdx.x, dir = blockIdx.z;
  int d = threadIdx.x;
  const float* dblP = dbl + (size_t)dir*Bsz*Ll*40;
  const unsigned short* xiP = xib + (size_t)dir*Bsz*Ll*256;
  size_t base = (size_t)b*Ll + (size_t)c*CH;
  if (d < CH*6){
    int p = d/6, j = d - p*6;
    *(float4*)&dblS[p*24 + j*4] = *(const float4*)&dblP[(base+p)*40 + j*4];
  }
  float A0 = A0C[dir*256 + d];
  bool chain = CHNf[dir*256 + d] != 0.f;
  f32x2 wv2[4];
  {
    const float* dw = dtw + (size_t)dir*2048 + d*8;
    float4 w0 = *(const float4*)&dw[0];
    float4 w1 = *(const float4*)&dw[4];
    wv2[0]=(f32x2){w0.x,w0.y}; wv2[1]=(f32x2){w0.z,w0.w};
    wv2[2]=(f32x2){w1.x,w1.y}; wv2[3]=(f32x2){w1.z,w1.w};
  }
  float bbt = dtb[dir*256 + d];
  __syncthreads();
  float sdt = 0.f;
  const unsigned short* xip = xiP + base*256 + d;
  size_t sbase = (size_t)dir*Bsz*NC*4096 + ((size_t)(b*NC + c))*4096 + (size_t)d*16;
  if (chain){
    bool n1 = fabsf(A0 + 1.f) < 1e-6f;   // A0 == -1: e1 = 1/(1+exp(a0)) exactly
    float xv[CH];
    #pragma unroll
    for (int p=0;p<CH;p++) xv[p] = bs2f(xip[(size_t)p*256]);
    f32x2 h2[8];
    #pragma unroll
    for (int i=0;i<8;i++) h2[i] = (f32x2){0.f,0.f};
    #pragma unroll
    for (int p=0;p<CH;p++){
      const float* rw = &dblS[p*24];
      f32x4 t0 = *(const f32x4*)&rw[0];
      f32x4 t1 = *(const f32x4*)&rw[4];
      f32x2 dp = pk_mul(lo2(t0), wv2[0]);
      dp = pk_fma(hi2(t0), wv2[1], dp);
      dp = pk_fma(lo2(t1), wv2[2], dp);
      dp = pk_fma(hi2(t1), wv2[3], dp);
      float a0 = bbt + dp.x + dp.y;
      float t = __expf(a0);
      float u = 1.f + t;
      float dtv = (a0>20.f)? a0 : __logf(u);
      float e1 = n1 ? __builtin_amdgcn_rcpf(u) : __expf(dtv*A0);
      float dx = dtv*xv[p];
      sdt += dtv;
      f32x2 pw2[8];
      POWTREE2(e1, pw2);
      f32x2 dxv = (f32x2){dx,dx};
      f32x4 b0 = *(const f32x4*)&dblS[p*24+8];
      f32x4 b1 = *(const f32x4*)&dblS[p*24+12];
      f32x4 b2 = *(const f32x4*)&dblS[p*24+16];
      f32x4 b3 = *(const f32x4*)&dblS[p*24+20];
      h2[0] = pk_fma(pw2[0], h2[0], pk_mul(lo2(b0), dxv));
      h2[1] = pk_fma(pw2[1], h2[1], pk_mul(hi2(b0), dxv));
      h2[2] = pk_fma(pw2[2], h2[2], pk_mul(lo2(b1), dxv));
      h2[3] = pk_fma(pw2[3], h2[3], pk_mul(hi2(b1), dxv));
      h2[4] = pk_fma(pw2[4], h2[4], pk_mul(lo2(b2), dxv));
      h2[5] = pk_fma(pw2[5], h2[5], pk_mul(hi2(b2), dxv));
      h2[6] = pk_fma(pw2[6], h2[6], pk_mul(lo2(b3), dxv));
      h2[7] = pk_fma(pw2[7], h2[7], pk_mul(hi2(b3), dxv));
    }
    #pragma unroll
    for (int j=0;j<4;j++)
      *(float4*)&Q[sbase + 4*j] = (float4){h2[2*j].x,h2[2*j].y,h2[2*j+1].x,h2[2*j+1].y};
  } else {
    float A[16];
    #pragma unroll
    for (int j=0;j<4;j++)
      *(float4*)&A[4*j] = *(const float4*)&AEX[(size_t)dir*4096 + d*16 + j*4];
    float h[16];
    #pragma unroll
    for (int n=0;n<16;n++) h[n]=0.f;
    for (int p=0;p<CH;p++){
      const float* rw = &dblS[p*24];
      float4 t0 = *(const float4*)&rw[0], t1 = *(const float4*)&rw[4];
      float a0 = bbt + t0.x*wv2[0].x+t0.y*wv2[0].y+t0.z*wv2[1].x+t0.w*wv2[1].y
                     + t1.x*wv2[2].x+t1.y*wv2[2].y+t1.z*wv2[3].x+t1.w*wv2[3].y;
      float dtv = (a0>20.f)? a0 : __logf(1.f+__expf(a0));
      float xiv = bs2f(xip[(size_t)p*256]);
      float dx = dtv*xiv;
      sdt += dtv;
      float bc[16];
      *(float4*)&bc[0]  = *(const float4*)&rw[8];
      *(float4*)&bc[4]  = *(const float4*)&rw[12];
      *(float4*)&bc[8]  = *(const float4*)&rw[16];
      *(float4*)&bc[12] = *(const float4*)&rw[20];
      #pragma unroll
      for (int n=0;n<16;n++){
        float a = __expf(dtv*A[n]);
        h[n] = a*h[n] + bc[n]*dx;
      }
    }
    #pragma unroll
    for (int j=0;j<4;j++)
      *(float4*)&Q[sbase + 4*j] = (float4){h[4*j],h[4*j+1],h[4*j+2],h[4*j+3]};
  }
  SD[(((size_t)dir*Bsz + b)*NC + c)*256 + d] = sdt;
}

// ---------------------------------------------------------------------------
// Phase 2a: group-local combine, PARALLEL over NG=16 chunk-groups.
// In-place: Q[c] -> group-local chunk-START state; SD[c] -> group-local
// prefix-sdt. Emits group aggregates SDG (total sdt) and QG (group-end H).
// ---------------------------------------------------------------------------
__global__ __launch_bounds__(64) void k_scan2a(float* __restrict__ SD, float* __restrict__ Q,
                        float* __restrict__ SDG, float* __restrict__ QG,
                        const float* __restrict__ AEX){
  int zb = blockIdx.z;                 // dir*Bsz + b
  int dir = zb >> 2;
  int g  = blockIdx.y;                 // group 0..15
  int t  = blockIdx.x*64 + threadIdx.x;  // 0..1023 state-quads
  int dn4 = t*4;
  int d = dn4 >> 4;
  float4 A4 = *(const float4*)&AEX[(size_t)dir*4096 + dn4];
  float* sd = SD + (((size_t)zb*NC) + (size_t)g*(NC/NG))*256 + d;
  float* q  = Q + (size_t)zb*NC*4096 + (size_t)g*(NC/NG)*4096 + dn4;
  float4 H = {0.f,0.f,0.f,0.f};
  float S = 0.f;
  #pragma unroll
  for (int c2=0; c2<NC/NG; c2++){
    float s_c = sd[(size_t)c2*256];
    float4 q_c = *(const float4*)(q + (size_t)c2*4096);
    sd[(size_t)c2*256] = S;
    *(float4*)(q + (size_t)c2*4096) = H;
    float4 p;
    p.x = __expf(A4.x*s_c); p.y = __expf(A4.y*s_c);
    p.z = __expf(A4.z*s_c); p.w = __expf(A4.w*s_c);
    H.x = p.x*H.x + q_c.x; H.y = p.y*H.y + q_c.y;
    H.z = p.z*H.z + q_c.z; H.w = p.w*H.w + q_c.w;
    S += s_c;
  }
  SDG[((size_t)zb*NG + g)*256 + d] = S;
  *(float4*)&QG[((size_t)zb*NG + g)*4096 + dn4] = H;
}

// Phase 2b: serial combine of NG=16 group aggregates. QG[g] is overwritten
// with the group-START absolute state.
__global__ __launch_bounds__(64) void k_scan2b(const float* __restrict__ SDG, float* __restrict__ QG,
                        const float* __restrict__ AEX){
  int b = blockIdx.y, dir = blockIdx.z;
  int zb = dir*Bsz + b;
  int t = blockIdx.x*64 + threadIdx.x;   // 0..1023
  int dn4 = t*4;
  int d = dn4 >> 4;
  float4 A4 = *(const float4*)&AEX[(size_t)dir*4096 + dn4];
  const float* sg = SDG + (size_t)zb*NG*256 + d;
  float* qg = QG + (size_t)zb*NG*4096 + dn4;
  float4 H = {0.f,0.f,0.f,0.f};
  #pragma unroll
  for (int g=0; g<NG; g++){
    float s = sg[(size_t)g*256];
    float4 qe = *(const float4*)(qg + (size_t)g*4096);
    *(float4*)(qg + (size_t)g*4096) = H;
    float4 p;
    p.x = __expf(A4.x*s); p.y = __expf(A4.y*s);
    p.z = __expf(A4.z*s); p.w = __expf(A4.w*s);
    H.x = p.x*H.x + qe.x; H.y = p.y*H.y + qe.y;
    H.z = p.z*H.z + qe.z; H.w = p.w*H.w + qe.w;
  }
}

// ---------------------------------------------------------------------------
// Phase 3: re-scan from start states. Chunk-start state reconstructed as
//   H_start(c) = exp(A*SD_prefix(c)) o QG[group(c)] + Q_local(c)   (exact).
// Writes RAW y (gating by silu(z) moved to gemm_out staging).
// ---------------------------------------------------------------------------
__global__ __launch_bounds__(256) void k_scan3(const float* __restrict__ dbl,
                       unsigned short* xiy, const float* __restrict__ AEX,
                       const float* __restrict__ A0C, const float* __restrict__ CHNf,
                       const float* __restrict__ dtw, const float* __restrict__ dtb,
                       const float* __restrict__ Dpw, const float* __restrict__ Hs,
                       const float* __restrict__ SDp, const float* __restrict__ QG){
  __shared__ float dblS[CH*40];
  int b = blockIdx.y, c = blockIdx.x, dir = blockIdx.z;
  int d = threadIdx.x;
  const float* dblP = dbl + (size_t)dir*Bsz*Ll*40;
  unsigned short* xiP = xiy + (size_t)dir*Bsz*Ll*256;
  size_t base = (size_t)b*Ll + (size_t)c*CH;
  for (int idx=d; idx<CH*10; idx+=256){
    int p = idx/10, j = idx - p*10;
    *(float4*)&dblS[p*40 + j*4] = *(const float4*)&dblP[(base+p)*40 + j*4];
  }
  float A0 = A0C[dir*256 + d];
  bool chain = CHNf[dir*256 + d] != 0.f;
  f32x2 wv2[4];
  {
    const float* dw = dtw + (size_t)dir*2048 + d*8;
    float4 w0 = *(const float4*)&dw[0];
    float4 w1 = *(const float4*)&dw[4];
    wv2[0]=(f32x2){w0.x,w0.y}; wv2[1]=(f32x2){w0.z,w0.w};
    wv2[2]=(f32x2){w1.x,w1.y}; wv2[3]=(f32x2){w1.z,w1.w};
  }
  float bbt = dtb[dir*256 + d];
  float Dp = Dpw[dir*256 + d];
  int zb = dir*Bsz + b;
  size_t sbase = (size_t)zb*NC*4096 + (size_t)c*4096 + (size_t)d*16;
  float sdtp = SDp[(((size_t)zb)*NC + c)*256 + d];
  size_t gbase = ((size_t)zb*NG + (c >> 4))*4096 + (size_t)d*16;
  __syncthreads();
  unsigned short* xip = xiP + base*256 + d;
  if (chain){
    bool n1 = fabsf(A0 + 1.f) < 1e-6f;
    float xv[CH];
    #pragma unroll
    for (int p=0;p<CH;p++) xv[p] = bs2f(xip[(size_t)p*256]);
    // reconstruct chunk-start state: h = pw(exp(A0*sdtp)) * QG + Qlocal
    f32x2 h2[8];
    {
      float eg = __expf(A0*sdtp);
      f32x2 pg[8];
      POWTREE2(eg, pg);
      #pragma unroll
      for (int j=0;j<4;j++){
        float4 h4 = *(const float4*)&Hs[sbase + 4*j];
        float4 g4 = *(const float4*)&QG[gbase + 4*j];
        h2[2*j]   = pk_fma(pg[2*j],   (f32x2){g4.x,g4.y}, (f32x2){h4.x,h4.y});
        h2[2*j+1] = pk_fma(pg[2*j+1], (f32x2){g4.z,g4.w}, (f32x2){h4.z,h4.w});
      }
    }
    #pragma unroll
    for (int p=0;p<CH;p++){
      const float* rw = &dblS[p*40];
      f32x4 t0 = *(const f32x4*)&rw[0];
      f32x4 t1 = *(const f32x4*)&rw[4];
      f32x2 dp = pk_mul(lo2(t0), wv2[0]);
      dp = pk_fma(hi2(t0), wv2[1], dp);
      dp = pk_fma(lo2(t1), wv2[2], dp);
      dp = pk_fma(hi2(t1), wv2[3], dp);
      float a0 = bbt + dp.x + dp.y;
      float t = __expf(a0);
      float u = 1.f + t;
      float dtv = (a0>20.f)? a0 : __logf(u);
      float e1 = n1 ? __builtin_amdgcn_rcpf(u) : __expf(dtv*A0);
      float dx = dtv*xv[p];
      f32x2 pw2[8];
      POWTREE2(e1, pw2);
      f32x2 dxv = (f32x2){dx,dx};
      f32x4 b0 = *(const f32x4*)&dblS[p*40+8];
      f32x4 b1 = *(const f32x4*)&dblS[p*40+12];
      f32x4 b2 = *(const f32x4*)&dblS[p*40+16];
      f32x4 b3 = *(const f32x4*)&dblS[p*40+20];
      f32x4 c0 = *(const f32x4*)&dblS[p*40+24];
      f32x4 c1 = *(const f32x4*)&dblS[p*40+28];
      f32x4 c2 = *(const f32x4*)&dblS[p*40+32];
      f32x4 c3 = *(const f32x4*)&dblS[p*40+36];
      f32x2 ya;
      h2[0] = pk_fma(pw2[0], h2[0], pk_mul(lo2(b0), dxv));
      ya = pk_mul(h2[0], lo2(c0));
      h2[1] = pk_fma(pw2[1], h2[1], pk_mul(hi2(b0), dxv));
      ya = pk_fma(h2[1], hi2(c0), ya);
      h2[2] = pk_fma(pw2[2], h2[2], pk_mul(lo2(b1), dxv));
      ya = pk_fma(h2[2], lo2(c1), ya);
      h2[3] = pk_fma(pw2[3], h2[3], pk_mul(hi2(b1), dxv));
      ya = pk_fma(h2[3], hi2(c1), ya);
      h2[4] = pk_fma(pw2[4], h2[4], pk_mul(lo2(b2), dxv));
      ya = pk_fma(h2[4], lo2(c2), ya);
      h2[5] = pk_fma(pw2[5], h2[5], pk_mul(hi2(b2), dxv));
      ya = pk_fma(h2[5], hi2(c2), ya);
      h2[6] = pk_fma(pw2[6], h2[6], pk_mul(lo2(b3), dxv));
      ya = pk_fma(h2[6], lo2(c3), ya);
      h2[7] = pk_fma(pw2[7], h2[7], pk_mul(hi2(b3), dxv));
      ya = pk_fma(h2[7], hi2(c3), ya);
      float acc = ya.x + ya.y;
      xip[(size_t)p*256] = f2bs(acc + Dp*xv[p]);
    }
  } else {
    float A[16];
    #pragma unroll
    for (int j=0;j<4;j++)
      *(float4*)&A[4*j] = *(const float4*)&AEX[(size_t)dir*4096 + d*16 + j*4];
    float h[16];
    #pragma unroll
    for (int j=0;j<4;j++){
      float4 h4 = *(const float4*)&Hs[sbase + 4*j];
      float4 g4 = *(const float4*)&QG[gbase + 4*j];
      h[4*j]   = __expf(A[4*j]*sdtp)*g4.x   + h4.x;
      h[4*j+1] = __expf(A[4*j+1]*sdtp)*g4.y + h4.y;
      h[4*j+2] = __expf(A[4*j+2]*sdtp)*g4.z + h4.z;
      h[4*j+3] = __expf(A[4*j+3]*sdtp)*g4.w + h4.w;
    }
    for (int p=0;p<CH;p++){
      const float* rw = &dblS[p*40];
      float4 t0 = *(const float4*)&rw[0], t1 = *(const float4*)&rw[4];
      float a0 = bbt + t0.x*wv2[0].x+t0.y*wv2[0].y+t0.z*wv2[1].x+t0.w*wv2[1].y
                     + t1.x*wv2[2].x+t1.y*wv2[2].y+t1.z*wv2[3].x+t1.w*wv2[3].y;
      float dtv = (a0>20.f)? a0 : __logf(1.f+__expf(a0));
      float xiv = bs2f(xip[(size_t)p*256]);
      float dx = dtv*xiv;
      float bc[16], cc[16];
      *(float4*)&bc[0]  = *(const float4*)&rw[8];
      *(float4*)&bc[4]  = *(const float4*)&rw[12];
      *(float4*)&bc[8]  = *(const float4*)&rw[16];
      *(float4*)&bc[12] = *(const float4*)&rw[20];
      *(float4*)&cc[0]  = *(const float4*)&rw[24];
      *(float4*)&cc[4]  = *(const float4*)&rw[28];
      *(float4*)&cc[8]  = *(const float4*)&rw[32];
      *(float4*)&cc[12] = *(const float4*)&rw[36];
      float acc = 0.f;
      #pragma unroll
      for (int n=0;n<16;n++){
        float a = __expf(dtv*A[n]);
        h[n] = a*h[n] + bc[n]*dx;
        acc += h[n]*cc[n];
      }
      xip[(size_t)p*256] = f2bs(acc + Dp*xiv);
    }
  }
}

// final transpose (B,L,128) fp32 -> (B,128,L) fp32
__global__ __launch_bounds__(256) void k_final(const float* __restrict__ hres, float* __restrict__ out){
  __shared__ float tile[64*129];
  int b = blockIdx.y, l0 = blockIdx.x*64;
  int tid = threadIdx.x;
  for (int q=0;q<32;q++){
    int idx = q*256 + tid;
    int l = idx >> 7, c = idx & 127;
    tile[l*129 + c] = hres[((size_t)b*Ll + l0 + l)*128 + c];
  }
  __syncthreads();
  int lo = tid & 63; int cbase = tid >> 6;
  for (int q=0;q<32;q++){
    int c = cbase + q*4;
    out[((size_t)b*128 + c)*Ll + l0 + lo] = tile[lo*129 + c];
  }
}

extern "C" void kernel_launch(void* const* d_in, const int* in_sizes, int n_in,
                              void* d_out, int out_size, void* d_ws, size_t ws_size,
                              hipStream_t stream){
  const float* x      = (const float*)d_in[0];
  const float* skip   = (const float*)d_in[1];
  const float* up_w   = (const float*)d_in[2];
  const float* up_b   = (const float*)d_in[3];
  const float* fus_w  = (const float*)d_in[4];
  const float* fus_b  = (const float*)d_in[5];
  const float* gn_w   = (const float*)d_in[6];
  const float* gn_b   = (const float*)d_in[7];
  const float* pa     = (const float*)d_in[8];
  const float* ln_w   = (const float*)d_in[9];
  const float* ln_b   = (const float*)d_in[10];
  const float* in_w   = (const float*)d_in[11];
  const float* conv_w = (const float*)d_in[12];
  const float* conv_b = (const float*)d_in[13];
  const float* xproj_w= (const float*)d_in[14];
  const float* dtproj_w=(const float*)d_in[15];
  const float* dtproj_b=(const float*)d_in[16];
  const float* A_log  = (const float*)d_in[17];
  const float* Dp     = (const float*)d_in[18];
  const float* out_w  = (const float*)d_in[19];

  // Workspace (~104 MiB). U1 holds XT+SKT (preamble) then SQ (loop).
  // SD (chunk sdt -> group prefix) and QG (group states) alias XNB exactly;
  // SDG is a small fresh allocation. All XNB aliases are dead by the time
  // gemm_out writes xn. y is written RAW to XIB2; gating happens in gemm_out.
  float* w = (float*)d_ws;
  size_t off=0;
  float* B2 = w+off; off += 128;
  float* GST= w+off; off += 16;
  off = (off+3)&~(size_t)3;
  float* HR = w+off; off += (size_t)Bsz*Ll*128;
  float* DBL2= w+off; off += 2*(size_t)Bsz*Ll*40;
  unsigned short* XNB = (unsigned short*)(w+off); off += (size_t)Bsz*Ll*128/2;
  unsigned short* XZB2= (unsigned short*)(w+off); off += 2*(size_t)Bsz*Ll*512/2;
  unsigned short* IWB = (unsigned short*)(w+off); off += 2*2*512*128/2;
  unsigned short* OWB = (unsigned short*)(w+off); off += 2*2*128*256/2;
  unsigned short* WXB = (unsigned short*)(w+off); off += 2*2*64*256/2;
  unsigned short* WEb = (unsigned short*)(w+off); off += 768*128/2;
  unsigned short* WOb = (unsigned short*)(w+off); off += 512*128/2;
  unsigned short* FWSb= (unsigned short*)(w+off); off += 128*128/2;
  float* AEXb = w+off; off += 4*4096;
  float* A0Cb = w+off; off += 4*256;
  float* CHNb = w+off; off += 4*256;
  float* SDGb = w+off; off += (size_t)2*Bsz*NG*256;   // 32K floats
  size_t planeS = (size_t)Bsz*NC*4096;       // 4,194,304 @ NC=256
  float* U1 = w+off; off += 2*planeS;        // SQ (and preamble XT/SKT)
  unsigned short* XT  = (unsigned short*)U1;
  unsigned short* SKT = (unsigned short*)(U1 + 1049604);
  float* SQ = U1;
  float* SD = (float*)XNB;                   // 524,288 floats
  float* QG = SD + 524288;                   // 524,288 floats (2*Bsz*NG*4096)
  float* U2 = w+off; off += 2*(size_t)Bsz*Ll*128;
  float* H0 = U2;
  unsigned short* XIB2 = (unsigned short*)U2;

  hipMemsetAsync(GST, 0, 16*sizeof(float), stream);
  k_cvt2<<<(2*2*512*128 + 2*2*128*256 + 255)/256,256,0,stream>>>(in_w, out_w, IWB, OWB,
                                                                 2*2*512*128, 2*2*128*256);
  k_prepx<<<dim3(64,4),256,0,stream>>>(xproj_w, WXB);
  k_prepA<<<4,256,0,stream>>>(A_log, AEXb, A0Cb, CHNb);
  k_compose<<<256,128,0,stream>>>(up_w, fus_w, fus_b, up_b, WEb, WOb, FWSb, B2);
  k_tx<<<dim3(Tt/64, 4, Bsz),256,0,stream>>>(x, XT);
  k_ts<<<dim3(Ll/64, 2, Bsz),256,0,stream>>>(skip, SKT);
  k_up<<<dim3(32, 2, Bsz),256,0,stream>>>(XT, SKT, WEb, WOb, FWSb, B2, H0, GST);
  k_gnln<<<Bsz*Ll/4,256,0,stream>>>(H0, gn_w, gn_b, pa, GST, ln_w, ln_b, HR, XNB);
  for (int i=0;i<2;i++){
    k_gemm_in<<<dim3(128,4,2),256,0,stream>>>(XNB, IWB + (size_t)(i*2)*512*128, XZB2);
    k_xproj3<<<dim3(Bsz*Ll/64,2),256,0,stream>>>(XZB2, WXB + (size_t)(i*2)*64*256,
                                                 conv_w + (i*2)*1024, conv_b + (i*2)*256,
                                                 XIB2, DBL2);
    k_scan1<<<dim3(NC,Bsz,2),256,0,stream>>>(DBL2, XIB2, AEXb + (size_t)(i*2)*4096,
                                             A0Cb + (i*2)*256, CHNb + (i*2)*256,
                                             dtproj_w + (i*2)*2048, dtproj_b + (i*2)*256, SD, SQ);
    k_scan2a<<<dim3(16,NG,2*Bsz),64,0,stream>>>(SD, SQ, SDGb, QG, AEXb + (size_t)(i*2)*4096);
    k_scan2b<<<dim3(16,Bsz,2),64,0,stream>>>(SDGb, QG, AEXb + (size_t)(i*2)*4096);
    k_scan3<<<dim3(NC,Bsz,2),256,0,stream>>>(DBL2, XIB2, AEXb + (size_t)(i*2)*4096,
                                             A0Cb + (i*2)*256, CHNb + (i*2)*256,
                                             dtproj_w + (i*2)*2048, dtproj_b + (i*2)*256,
                                             Dp + (i*2)*256, SQ, SD, QG);
    if (i==0)
      k_gemm_out_t<1><<<256,256,0,stream>>>(XIB2, XZB2, OWB + 0, HR, ln_w + 128, ln_b + 128, XNB);
    else
      k_gemm_out_t<0><<<256,256,0,stream>>>(XIB2, XZB2, OWB + (size_t)2*128*256, HR,
                                            (const float*)nullptr, (const float*)nullptr,
                                            (unsigned short*)nullptr);
  }
  k_final<<<dim3(Ll/64,Bsz),256,0,stream>>>(HR, (float*)d_out);
}

// Round 9
// 379.561 us; speedup vs baseline: 1.0825x; 1.0825x over previous
//
#include <hip/hip_runtime.h>
#include <hip/hip_bf16.h>

#define Bsz 4
#define Tt 2048
#define Ll 4096
#define NC 256     // chunks for scan (2048 blocks/dispatch batched over dirs)
#define CH 16      // steps per chunk (NC*CH == Ll)
#define NG 16      // chunk groups for hierarchical combine (NC/NG = 16 chunks/group)

typedef short bf16x8 __attribute__((ext_vector_type(8)));
typedef float f32x4 __attribute__((ext_vector_type(4)));
typedef float f32x2 __attribute__((ext_vector_type(2)));

// Forced VOP3P packed fp32 (compiler may scalarize <2 x float> otherwise).
static __device__ __forceinline__ f32x2 pk_fma(f32x2 a, f32x2 b, f32x2 c){
  f32x2 d;
  asm("v_pk_fma_f32 %0, %1, %2, %3" : "=v"(d) : "v"(a), "v"(b), "v"(c));
  return d;
}
static __device__ __forceinline__ f32x2 pk_mul(f32x2 a, f32x2 b){
  f32x2 d;
  asm("v_pk_mul_f32 %0, %1, %2" : "=v"(d) : "v"(a), "v"(b));
  return d;
}
static __device__ __forceinline__ f32x2 lo2(f32x4 v){ return (f32x2){v.x, v.y}; }
static __device__ __forceinline__ f32x2 hi2(f32x4 v){ return (f32x2){v.z, v.w}; }

static __device__ __forceinline__ float bs2f(unsigned short u){
  union{float f; unsigned int i;} v; v.i = ((unsigned int)u)<<16; return v.f;
}
static __device__ __forceinline__ unsigned short f2bs(float f){
  union{float f; unsigned int i;} v; v.f = f;
  unsigned int r = (v.i + 0x7fffu + ((v.i>>16)&1u)) >> 16;
  return (unsigned short)r;
}
// fp16 side-channel for dtv (v_cvt_f16_f32 / v_cvt_f32_f16)
static __device__ __forceinline__ unsigned short f2h(float f){
  union{_Float16 h; unsigned short u;} v; v.h = (_Float16)f; return v.u;
}
static __device__ __forceinline__ float h2f(unsigned short u){
  union{_Float16 h; unsigned short u;} v; v.u = u; return (float)v.h;
}

// fp32 -> bf16 bulk convert, two source/dest pairs in one dispatch
__global__ void k_cvt2(const float* __restrict__ a, const float* __restrict__ b,
                       unsigned short* __restrict__ da, unsigned short* __restrict__ db,
                       int na, int nb){
  int i = blockIdx.x*256 + threadIdx.x;
  if (i < na) da[i] = f2bs(a[i]);
  else {
    int j = i - na;
    if (j < nb) db[j] = f2bs(b[j]);
  }
}

// pad xproj_w (4 branches, 40x256) to zero-filled 64x256 bf16
__global__ void k_prepx(const float* __restrict__ xw, unsigned short* __restrict__ wxb){
  int row = blockIdx.x, br = blockIdx.y, col = threadIdx.x;
  float v = (row < 40) ? xw[((size_t)br*40 + row)*256 + col] : 0.f;
  wxb[((size_t)br*64 + row)*256 + col] = f2bs(v);
}

// Precompute AEX = -exp(A_log) (4 branches x 4096), per-(br,d) A0 + chain flag.
__global__ void k_prepA(const float* __restrict__ Alog, float* __restrict__ AEX,
                        float* __restrict__ A0C, float* __restrict__ CHN){
  int br = blockIdx.x, d = threadIdx.x;
  float A[16];
  #pragma unroll
  for (int j=0;j<4;j++){
    float4 a4 = *(const float4*)&Alog[(size_t)br*4096 + d*16 + j*4];
    A[4*j]  = -__expf(a4.x); A[4*j+1] = -__expf(a4.y);
    A[4*j+2]= -__expf(a4.z); A[4*j+3] = -__expf(a4.w);
    *(float4*)&AEX[(size_t)br*4096 + d*16 + j*4] = (float4){A[4*j],A[4*j+1],A[4*j+2],A[4*j+3]};
  }
  bool chain = true;
  #pragma unroll
  for (int n=1;n<16;n++){
    float expect = A[0]*(float)(n+1);
    if (fabsf(A[n]-expect) > 1e-3f*fabsf(expect)) chain = false;
  }
  A0C[br*256 + d] = A[0];
  CHN[br*256 + d] = chain ? 1.f : 0.f;
}

// ---------------------------------------------------------------------------
// Compose upsample-conv weights with fuse matmul; emit bf16 GEMM-ready layouts.
// ---------------------------------------------------------------------------
__global__ void k_compose(const float* __restrict__ up_w, const float* __restrict__ fus_w,
                          const float* __restrict__ fus_b, const float* __restrict__ up_b,
                          unsigned short* __restrict__ WEb, unsigned short* __restrict__ WOb,
                          unsigned short* __restrict__ FWSb, float* __restrict__ BIAS2){
  int i = blockIdx.x;     // 0..255
  int o = threadIdx.x;    // 0..127
  float a0=0.f,a1=0.f,a2=0.f,a3=0.f,a4=0.f;
  for (int c=0;c<256;c++){
    float f = fus_w[o*384+c];
    const float* w = up_w + ((size_t)i*256+c)*5;
    a0 += f*w[0]; a1 += f*w[1]; a2 += f*w[2];
    a3 += f*w[3]; a4 += f*w[4];
  }
  WEb[(size_t)o*768 +       i] = f2bs(a4);
  WEb[(size_t)o*768 + 256 + i] = f2bs(a2);
  WEb[(size_t)o*768 + 512 + i] = f2bs(a0);
  WOb[(size_t)o*512 +       i] = f2bs(a3);
  WOb[(size_t)o*512 + 256 + i] = f2bs(a1);
  if (i<128) FWSb[o*128 + i] = f2bs(fus_w[o*384+256+i]);
  if (i==0){
    float bb = fus_b[o];
    for (int c=0;c<256;c++) bb += fus_w[o*384+c]*up_b[c];
    BIAS2[o]=bb;
  }
}

// transpose x (B,256,T) f32 -> XT (B, T+2, 256) bf16, row t stored at t+1.
// Halo rows (t=-1 and t=2048) zeroed by the (0,0,b) blocks.
__global__ __launch_bounds__(256) void k_tx(const float* __restrict__ x, unsigned short* __restrict__ XT){
  __shared__ float tile[64][65];
  int b=blockIdx.z, t0=blockIdx.x*64, i0=blockIdx.y*64;
  int tid=threadIdx.x;
  if (blockIdx.x==0 && blockIdx.y==0){
    XT[((size_t)b*2050)*256 + tid] = 0;
    XT[((size_t)b*2050+2049)*256 + tid] = 0;
  }
  for (int it=0;it<16;it++){
    int idx=it*256+tid; int ii=idx>>6, tt=idx&63;
    tile[ii][tt] = x[((size_t)b*256+i0+ii)*Tt + t0+tt];
  }
  __syncthreads();
  for (int it=0;it<16;it++){
    int idx=it*256+tid; int tt=idx>>6, ii=idx&63;
    XT[((size_t)b*2050 + t0+tt+1)*256 + i0+ii] = f2bs(tile[ii][tt]);
  }
}

// transpose skip (B,128,L) f32 -> SKT (B,L,128) bf16
__global__ __launch_bounds__(256) void k_ts(const float* __restrict__ skip, unsigned short* __restrict__ SKT){
  __shared__ float tile[64][65];
  int b=blockIdx.z, l0=blockIdx.x*64, s0=blockIdx.y*64;
  int tid=threadIdx.x;
  for (int it=0;it<16;it++){
    int idx=it*256+tid; int ss=idx>>6, ll=idx&63;
    tile[ss][ll] = skip[((size_t)b*128+s0+ss)*Ll + l0+ll];
  }
  __syncthreads();
  for (int it=0;it<16;it++){
    int idx=it*256+tid; int ll=idx>>6, ss=idx&63;
    SKT[((size_t)b*Ll + l0+ll)*128 + s0+ss] = f2bs(tile[ss][ll]);
  }
}

// ---------------------------------------------------------------------------
// MFMA upsample+fuse. Block = 64 t x 128 o, one parity.
// ---------------------------------------------------------------------------
__global__ __launch_bounds__(256) void k_up(const unsigned short* __restrict__ XT,
                     const unsigned short* __restrict__ SKT,
                     const unsigned short* __restrict__ WEb, const unsigned short* __restrict__ WOb,
                     const unsigned short* __restrict__ FWSb, const float* __restrict__ B2,
                     float* __restrict__ h0, float* __restrict__ gst){
  __shared__ unsigned short XL[66*264];
  __shared__ unsigned short Wb[128*72];
  __shared__ float red0[256], red1[256];
  int bt = blockIdx.x, par = blockIdx.y, b = blockIdx.z;
  int t0 = bt*64;
  int tid = threadIdx.x;
  int wave = tid>>6, lane = tid&63;
  int wm = wave>>1, wn = wave&1;
  int quad = lane>>4, l16 = lane&15;

  for (int idx=tid; idx<66*32; idx+=256){
    int row = idx>>5, c8 = idx&31;
    *(uint4*)&XL[row*264 + c8*8] = *(const uint4*)&XT[((size_t)b*2050 + t0 + row)*256 + c8*8];
  }

  const unsigned short* Wsrc = par ? WOb : WEb;
  const int Kw = par ? 512 : 768;
  const int tapbase = par ? 1 : 0;
  f32x4 acc[2][4];
  #pragma unroll
  for (int i=0;i<2;i++)
    #pragma unroll
    for (int j=0;j<4;j++) acc[i][j] = (f32x4){0.f,0.f,0.f,0.f};

  int nch = Kw>>6;
  for (int kc=0; kc<nch; kc++){
    __syncthreads();
    #pragma unroll
    for (int it=0; it<4; it++){
      int idx = it*256+tid;
      int row = idx>>3, c8 = idx&7;
      *(uint4*)&Wb[row*72 + c8*8] = *(const uint4*)&Wsrc[(size_t)row*Kw + kc*64 + c8*8];
    }
    __syncthreads();
    #pragma unroll
    for (int ks=0; ks<64; ks+=32){
      int kg = kc*64 + ks;
      int tap = kg>>8, ib = kg&255;
      bf16x8 af[2], bf[4];
      #pragma unroll
      for (int mt=0;mt<2;mt++)
        af[mt] = *(bf16x8*)&XL[(wm*32+mt*16+l16 + tapbase + tap)*264 + ib + quad*8];
      #pragma unroll
      for (int nt=0;nt<4;nt++)
        bf[nt] = *(bf16x8*)&Wb[(wn*64+nt*16+l16)*72 + ks + quad*8];
      #pragma unroll
      for (int mt=0;mt<2;mt++)
        #pragma unroll
        for (int nt=0;nt<4;nt++)
          acc[mt][nt] = __builtin_amdgcn_mfma_f32_16x16x32_bf16(af[mt], bf[nt], acc[mt][nt], 0,0,0);
    }
  }

  __syncthreads();
  for (int idx=tid; idx<64*16; idx+=256){
    int row = idx>>4, c8 = idx&15;
    *(uint4*)&XL[row*136 + c8*8] = *(const uint4*)&SKT[((size_t)b*Ll + 2*(t0+row)+par)*128 + c8*8];
  }
  for (int kc=0; kc<2; kc++){
    __syncthreads();
    #pragma unroll
    for (int it=0; it<4; it++){
      int idx = it*256+tid;
      int row = idx>>3, c8 = idx&7;
      *(uint4*)&Wb[row*72 + c8*8] = *(const uint4*)&FWSb[(size_t)row*128 + kc*64 + c8*8];
    }
    __syncthreads();
    #pragma unroll
    for (int ks=0; ks<64; ks+=32){
      bf16x8 af[2], bf[4];
      #pragma unroll
      for (int mt=0;mt<2;mt++)
        af[mt] = *(bf16x8*)&XL[(wm*32+mt*16+l16)*136 + kc*64 + ks + quad*8];
      #pragma unroll
      for (int nt=0;nt<4;nt++)
        bf[nt] = *(bf16x8*)&Wb[(wn*64+nt*16+l16)*72 + ks + quad*8];
      #pragma unroll
      for (int mt=0;mt<2;mt++)
        #pragma unroll
        for (int nt=0;nt<4;nt++)
          acc[mt][nt] = __builtin_amdgcn_mfma_f32_16x16x32_bf16(af[mt], bf[nt], acc[mt][nt], 0,0,0);
    }
  }

  float s1=0.f, s2=0.f;
  #pragma unroll
  for (int mt=0;mt<2;mt++)
    #pragma unroll
    for (int nt=0;nt<4;nt++)
      #pragma unroll
      for (int r=0;r<4;r++){
        int m = wm*32 + mt*16 + quad*4 + r;
        int lrow = 2*(t0+m) + par;
        int col = wn*64 + nt*16 + l16;
        float v = acc[mt][nt][r] + B2[col];
        h0[((size_t)b*Ll + lrow)*128 + col] = v;
        s1 += v; s2 += v*v;
      }
  red0[tid]=s1; red1[tid]=s2;
  __syncthreads();
  for (int st=128; st>0; st>>=1){
    if (tid<st){ red0[tid]+=red0[tid+st]; red1[tid]+=red1[tid+st]; }
    __syncthreads();
  }
  if (tid==0){ atomicAdd(&gst[b*2], red0[0]); atomicAdd(&gst[b*2+1], red1[0]); }
}

// Fused GroupNorm-apply + PReLU + layer-0 LayerNorm (stats from raw sums).
__global__ __launch_bounds__(256) void k_gnln(const float* __restrict__ h0, const float* __restrict__ gn_w,
                      const float* __restrict__ gn_b, const float* __restrict__ pa,
                      const float* __restrict__ gst, const float* __restrict__ lnw,
                      const float* __restrict__ lnb, float* __restrict__ hres,
                      unsigned short* __restrict__ xn){
  int row = blockIdx.x*4 + (threadIdx.x>>6);
  int lane = threadIdx.x & 63;
  int b = row >> 12;
  const float ninv = 1.f/((float)Ll*128.f);
  float mu_g = gst[b*2]*ninv;
  float var_g = gst[b*2+1]*ninv - mu_g*mu_g;
  float inv_g = rsqrtf(var_g + 1e-5f);
  float a = pa[0];
  const float* hp = h0 + (size_t)row*128;
  float u0 = (hp[lane]   -mu_g)*inv_g*gn_w[lane]    + gn_b[lane];
  float u1 = (hp[lane+64]-mu_g)*inv_g*gn_w[lane+64] + gn_b[lane+64];
  float v0 = u0>=0.f ? u0 : a*u0;
  float v1 = u1>=0.f ? u1 : a*u1;
  float* rp = hres + (size_t)row*128;
  rp[lane] = v0; rp[lane+64] = v1;
  float s = v0+v1, q = v0*v0+v1*v1;
  #pragma unroll
  for (int off=32; off>0; off>>=1){
    s += __shfl_xor(s, off, 64);
    q += __shfl_xor(q, off, 64);
  }
  float mu = s*(1.f/128.f);
  float rs = rsqrtf(q*(1.f/128.f)-mu*mu + 1e-5f);
  unsigned short* xp = xn + (size_t)row*128;
  xp[lane]    = f2bs((v0-mu)*rs*lnw[lane]    + lnb[lane]);
  xp[lane+64] = f2bs((v1-mu)*rs*lnw[lane+64] + lnb[lane+64]);
}

// ---------------------------------------------------------------------------
// MFMA GEMM in_proj, batched over dirs (blockIdx.z): XZ2[dir] = rev_dir(XN) @ W_dir^T
// ---------------------------------------------------------------------------
__global__ __launch_bounds__(256) void k_gemm_in(const unsigned short* __restrict__ A,
                          const unsigned short* __restrict__ W,
                          unsigned short* __restrict__ C){
  __shared__ unsigned short As[128*72];
  __shared__ unsigned short Bs[128*72];
  int tid = threadIdx.x;
  int row0 = blockIdx.x*128;
  int n0   = blockIdx.y*128;
  int dir  = blockIdx.z;
  const unsigned short* Wp = W + (size_t)dir*512*128;
  unsigned short* Cp = C + (size_t)dir*Bsz*Ll*512;
  int wave = tid>>6, lane = tid&63;
  int wm = wave>>1, wn = wave&1;
  int quad = lane>>4, l16 = lane&15;
  f32x4 acc[4][4];
  #pragma unroll
  for (int i=0;i<4;i++)
    #pragma unroll
    for (int j=0;j<4;j++) acc[i][j] = (f32x4){0.f,0.f,0.f,0.f};

  for (int kb=0; kb<128; kb+=64){
    __syncthreads();
    #pragma unroll
    for (int it=0; it<4; it++){
      int idx = it*256 + tid;
      int row = idx>>3, c8 = idx&7;
      int r = row0 + row;
      int p = r & (Ll-1); int bb = r >> 12;
      int src = (bb<<12) + (dir ? (Ll-1-p) : p);
      *(uint4*)&As[row*72 + c8*8] = *(const uint4*)&A[(size_t)src*128 + kb + c8*8];
      *(uint4*)&Bs[row*72 + c8*8] = *(const uint4*)&Wp[(size_t)(n0+row)*128 + kb + c8*8];
    }
    __syncthreads();
    #pragma unroll
    for (int ks=0; ks<64; ks+=32){
      bf16x8 af[4], bf[4];
      #pragma unroll
      for (int mt=0;mt<4;mt++)
        af[mt] = *(bf16x8*)&As[(wm*64+mt*16+l16)*72 + ks + quad*8];
      #pragma unroll
      for (int nt=0;nt<4;nt++)
        bf[nt] = *(bf16x8*)&Bs[(wn*64+nt*16+l16)*72 + ks + quad*8];
      #pragma unroll
      for (int mt=0;mt<4;mt++)
        #pragma unroll
        for (int nt=0;nt<4;nt++)
          acc[mt][nt] = __builtin_amdgcn_mfma_f32_16x16x32_bf16(af[mt], bf[nt], acc[mt][nt], 0,0,0);
    }
  }
  #pragma unroll
  for (int mt=0;mt<4;mt++)
    #pragma unroll
    for (int nt=0;nt<4;nt++)
      #pragma unroll
      for (int r=0;r<4;r++){
        int row = row0 + wm*64 + mt*16 + quad*4 + r;
        int col = n0 + wn*64 + nt*16 + l16;
        Cp[(size_t)row*512 + col] = f2bs(acc[mt][nt][r]);
      }
}

// ---------------------------------------------------------------------------
// Combined out_proj: HR[l] += Y0[l]@W0^T + Y1[rev l]@W1^T  (K=512, both dirs)
// Y holds the GATED scan output. DO_LN=1: LayerNorm rows -> bf16 xn.
// ---------------------------------------------------------------------------
template<int DO_LN>
__global__ __launch_bounds__(256) void k_gemm_out_t(const unsigned short* __restrict__ Y,
                           const unsigned short* __restrict__ W,
                           float* __restrict__ C, const float* __restrict__ lnw,
                           const float* __restrict__ lnb, unsigned short* __restrict__ xn){
  __shared__ unsigned short As[64*72];
  __shared__ unsigned short Bs[128*72];
  __shared__ float redS[2][4][2][4][2][2];   // [wm][quad][mt][r][wn][{s,q}]
  int tid = threadIdx.x;
  int row0 = blockIdx.x*64;
  int wave = tid>>6, lane = tid&63;
  int wm = wave>>1, wn = wave&1;
  int quad = lane>>4, l16 = lane&15;
  const size_t planeY = (size_t)Bsz*Ll*256;
  f32x4 acc[2][4];
  #pragma unroll
  for (int i=0;i<2;i++)
    #pragma unroll
    for (int j=0;j<4;j++) acc[i][j] = (f32x4){0.f,0.f,0.f,0.f};

  for (int kc=0; kc<8; kc++){
    int dirp = kc>>2;
    int kb = (kc&3)*64;
    const unsigned short* Wp = W + (size_t)dirp*128*256;
    __syncthreads();
    #pragma unroll
    for (int it=0; it<2; it++){
      int idx = it*256 + tid;
      int row = idx>>3, c8 = idx&7;
      int r = row0 + row;
      int p = r & (Ll-1); int bb = r >> 12;
      int srow = dirp ? ((bb<<12) + (Ll-1-p)) : r;
      *(uint4*)&As[row*72 + c8*8] = *(const uint4*)&Y[dirp*planeY + (size_t)srow*256 + kb + c8*8];
    }
    #pragma unroll
    for (int it=0; it<4; it++){
      int idx = it*256 + tid;
      int row = idx>>3, c8 = idx&7;
      *(uint4*)&Bs[row*72 + c8*8] = *(const uint4*)&Wp[(size_t)row*256 + kb + c8*8];
    }
    __syncthreads();
    #pragma unroll
    for (int ks=0; ks<64; ks+=32){
      bf16x8 af[2], bf[4];
      #pragma unroll
      for (int mt=0;mt<2;mt++)
        af[mt] = *(bf16x8*)&As[(wm*32+mt*16+l16)*72 + ks + quad*8];
      #pragma unroll
      for (int nt=0;nt<4;nt++)
        bf[nt] = *(bf16x8*)&Bs[(wn*64+nt*16+l16)*72 + ks + quad*8];
      #pragma unroll
      for (int mt=0;mt<2;mt++)
        #pragma unroll
        for (int nt=0;nt<4;nt++)
          acc[mt][nt] = __builtin_amdgcn_mfma_f32_16x16x32_bf16(af[mt], bf[nt], acc[mt][nt], 0,0,0);
    }
  }

  // epilogue: C += acc (keep final values in regs for LN)
  float vals[2][4][4];
  #pragma unroll
  for (int mt=0;mt<2;mt++)
    #pragma unroll
    for (int nt=0;nt<4;nt++)
      #pragma unroll
      for (int r=0;r<4;r++){
        int row = row0 + wm*32 + mt*16 + quad*4 + r;
        int col = wn*64 + nt*16 + l16;
        float v = C[(size_t)row*128 + col] + acc[mt][nt][r];
        C[(size_t)row*128 + col] = v;
        vals[mt][nt][r] = v;
      }

  if (DO_LN){
    // per-(mt,r) partial sums over this thread's 4 cols, then 16-lane reduce
    #pragma unroll
    for (int mt=0;mt<2;mt++)
      #pragma unroll
      for (int r=0;r<4;r++){
        float s = 0.f, q = 0.f;
        #pragma unroll
        for (int nt=0;nt<4;nt++){ float v = vals[mt][nt][r]; s += v; q += v*v; }
        #pragma unroll
        for (int off=1; off<16; off<<=1){
          s += __shfl_xor(s, off, 64);
          q += __shfl_xor(q, off, 64);
        }
        if (l16 == 0){
          redS[wm][quad][mt][r][wn][0] = s;
          redS[wm][quad][mt][r][wn][1] = q;
        }
      }
    __syncthreads();
    #pragma unroll
    for (int mt=0;mt<2;mt++)
      #pragma unroll
      for (int r=0;r<4;r++){
        float s = redS[wm][quad][mt][r][0][0] + redS[wm][quad][mt][r][1][0];
        float q = redS[wm][quad][mt][r][0][1] + redS[wm][quad][mt][r][1][1];
        float mu = s*(1.f/128.f);
        float rs = rsqrtf(q*(1.f/128.f) - mu*mu + 1e-5f);
        int row = row0 + wm*32 + mt*16 + quad*4 + r;
        #pragma unroll
        for (int nt=0;nt<4;nt++){
          int col = wn*64 + nt*16 + l16;
          xn[(size_t)row*128 + col] = f2bs((vals[mt][nt][r]-mu)*rs*lnw[col] + lnb[col]);
        }
      }
  }
}

// ---------------------------------------------------------------------------
// Fused depthwise conv (K=4, sliding window) + SiLU + MFMA x_proj.
// ---------------------------------------------------------------------------
__global__ __launch_bounds__(256) void k_xproj3(const unsigned short* __restrict__ xz,
                        const unsigned short* __restrict__ wxb,
                        const float* __restrict__ cw, const float* __restrict__ cb,
                        unsigned short* __restrict__ xib, float* __restrict__ dbl){
  __shared__ unsigned short xiS[64*264];
  __shared__ unsigned short Bs[64*72];
  int tid = threadIdx.x;
  int dir = blockIdx.y;
  xz  += (size_t)dir*Bsz*Ll*512;
  wxb += (size_t)dir*64*256;
  cw  += dir*1024;
  cb  += dir*256;
  xib += (size_t)dir*Bsz*Ll*256;
  dbl += (size_t)dir*Bsz*Ll*40;
  size_t row0 = (size_t)blockIdx.x*64;
  int p0 = (int)(row0 & (Ll-1));

  {
    int d = tid;
    float4 w4 = *(const float4*)&cw[d*4];
    float bias = cb[d];
    float w0, w1, w2;
    if (p0 == 0){ w0=0.f; w1=0.f; w2=0.f; }
    else {
      w0 = bs2f(xz[(row0-3)*512 + d]);
      w1 = bs2f(xz[(row0-2)*512 + d]);
      w2 = bs2f(xz[(row0-1)*512 + d]);
    }
    #pragma unroll 4
    for (int rr=0; rr<64; rr++){
      float xv = bs2f(xz[(row0+rr)*512 + d]);
      float acc = bias + w4.x*w0 + w4.y*w1 + w4.z*w2 + w4.w*xv;
      float v = acc*__builtin_amdgcn_rcpf(1.f+__expf(-acc));
      unsigned short us = f2bs(v);
      xiS[rr*264 + d] = us;
      xib[(row0+rr)*256 + d] = us;
      w0=w1; w1=w2; w2=xv;
    }
  }

  int wave = tid>>6, lane = tid&63;
  int quad = lane>>4, l16 = lane&15;
  f32x4 acc[4];
  #pragma unroll
  for (int j=0;j<4;j++) acc[j] = (f32x4){0.f,0.f,0.f,0.f};

  for (int kb=0; kb<256; kb+=64){
    __syncthreads();
    #pragma unroll
    for (int it=0; it<2; it++){
      int idx = it*256 + tid;
      int row = idx>>3, c8 = idx&7;
      *(uint4*)&Bs[row*72 + c8*8] = *(const uint4*)&wxb[(size_t)row*256 + kb + c8*8];
    }
    __syncthreads();
    #pragma unroll
    for (int ks=0; ks<64; ks+=32){
      bf16x8 af = *(bf16x8*)&xiS[(wave*16+l16)*264 + kb + ks + quad*8];
      #pragma unroll
      for (int nt=0;nt<4;nt++){
        bf16x8 bf = *(bf16x8*)&Bs[(nt*16+l16)*72 + ks + quad*8];
        acc[nt] = __builtin_amdgcn_mfma_f32_16x16x32_bf16(af, bf, acc[nt], 0,0,0);
      }
    }
  }
  #pragma unroll
  for (int nt=0;nt<4;nt++)
    #pragma unroll
    for (int r=0;r<4;r++){
      int m = wave*16 + quad*4 + r;
      int col = nt*16 + l16;
      if (col < 40) dbl[(row0+m)*40 + col] = acc[nt][r];
    }
}

// Packed pw2[i] = {e1^(2i+1), e1^(2i+2)}: 1 scalar mul + 7 packed muls (forced VOP3P).
#define POWTREE2(e1, pw2) { \
  float _e2 = (e1)*(e1); \
  f32x2 _e2v = (f32x2){_e2,_e2}; \
  pw2[0] = (f32x2){(e1),_e2}; \
  pw2[1] = pk_mul(pw2[0], _e2v); \
  pw2[2] = pk_mul(pw2[1], _e2v); \
  pw2[3] = pk_mul(pw2[2], _e2v); \
  f32x2 _e8v = (f32x2){pw2[3].y, pw2[3].y}; \
  pw2[4] = pk_mul(pw2[0], _e8v); \
  pw2[5] = pk_mul(pw2[1], _e8v); \
  pw2[6] = pk_mul(pw2[2], _e8v); \
  pw2[7] = pk_mul(pw2[3], _e8v); }

// ---------------------------------------------------------------------------
// Phase 1: chunk-local scan. Emits per-chunk sdt + chunk-end local states Q,
// and stores per-step dtv (fp16) into the DEAD x-half of the xz plane for
// phase-3 reuse (kills phase-3's dt-chain recompute).
// ---------------------------------------------------------------------------
__global__ __launch_bounds__(256) void k_scan1(const float* __restrict__ dbl,
                       const unsigned short* __restrict__ xib,
                       unsigned short* __restrict__ xz,
                       const float* __restrict__ AEX,
                       const float* __restrict__ A0C, const float* __restrict__ CHNf,
                       const float* __restrict__ dtw, const float* __restrict__ dtb,
                       float* __restrict__ SD, float* __restrict__ Q){
  __shared__ float dblS[CH*24];
  int b = blockIdx.y, c = blockIdx.x, dir = blockIdx.z;
  int d = threadIdx.x;
  const float* dblP = dbl + (size_t)dir*Bsz*Ll*40;
  const unsigned short* xiP = xib + (size_t)dir*Bsz*Ll*256;
  unsigned short* xzP = xz + (size_t)dir*Bsz*Ll*512;
  size_t base = (size_t)b*Ll + (size_t)c*CH;
  if (d < CH*6){
    int p = d/6, j = d - p*6;
    *(float4*)&dblS[p*24 + j*4] = *(const float4*)&dblP[(base+p)*40 + j*4];
  }
  float A0 = A0C[dir*256 + d];
  bool chain = CHNf[dir*256 + d] != 0.f;
  f32x2 wv2[4];
  {
    const float* dw = dtw + (size_t)dir*2048 + d*8;
    float4 w0 = *(const float4*)&dw[0];
    float4 w1 = *(const float4*)&dw[4];
    wv2[0]=(f32x2){w0.x,w0.y}; wv2[1]=(f32x2){w0.z,w0.w};
    wv2[2]=(f32x2){w1.x,w1.y}; wv2[3]=(f32x2){w1.z,w1.w};
  }
  float bbt = dtb[dir*256 + d];
  __syncthreads();
  float sdt = 0.f;
  const unsigned short* xip = xiP + base*256 + d;
  unsigned short* dtp = xzP + base*512 + d;      // x-half (dead after xproj3)
  size_t sbase = (size_t)dir*Bsz*NC*4096 + ((size_t)(b*NC + c))*4096 + (size_t)d*16;
  if (chain){
    bool n1 = fabsf(A0 + 1.f) < 1e-6f;   // A0 == -1: e1 = 1/(1+exp(a0)) exactly
    float xv[CH];
    #pragma unroll
    for (int p=0;p<CH;p++) xv[p] = bs2f(xip[(size_t)p*256]);
    f32x2 h2[8];
    #pragma unroll
    for (int i=0;i<8;i++) h2[i] = (f32x2){0.f,0.f};
    #pragma unroll
    for (int p=0;p<CH;p++){
      const float* rw = &dblS[p*24];
      f32x4 t0 = *(const f32x4*)&rw[0];
      f32x4 t1 = *(const f32x4*)&rw[4];
      f32x2 dp = pk_mul(lo2(t0), wv2[0]);
      dp = pk_fma(hi2(t0), wv2[1], dp);
      dp = pk_fma(lo2(t1), wv2[2], dp);
      dp = pk_fma(hi2(t1), wv2[3], dp);
      float a0 = bbt + dp.x + dp.y;
      float t = __expf(a0);
      float u = 1.f + t;
      float dtv = (a0>20.f)? a0 : __logf(u);
      float e1 = n1 ? __builtin_amdgcn_rcpf(u) : __expf(dtv*A0);
      dtp[(size_t)p*512] = f2h(dtv);
      float dx = dtv*xv[p];
      sdt += dtv;
      f32x2 pw2[8];
      POWTREE2(e1, pw2);
      f32x2 dxv = (f32x2){dx,dx};
      f32x4 b0 = *(const f32x4*)&dblS[p*24+8];
      f32x4 b1 = *(const f32x4*)&dblS[p*24+12];
      f32x4 b2 = *(const f32x4*)&dblS[p*24+16];
      f32x4 b3 = *(const f32x4*)&dblS[p*24+20];
      h2[0] = pk_fma(pw2[0], h2[0], pk_mul(lo2(b0), dxv));
      h2[1] = pk_fma(pw2[1], h2[1], pk_mul(hi2(b0), dxv));
      h2[2] = pk_fma(pw2[2], h2[2], pk_mul(lo2(b1), dxv));
      h2[3] = pk_fma(pw2[3], h2[3], pk_mul(hi2(b1), dxv));
      h2[4] = pk_fma(pw2[4], h2[4], pk_mul(lo2(b2), dxv));
      h2[5] = pk_fma(pw2[5], h2[5], pk_mul(hi2(b2), dxv));
      h2[6] = pk_fma(pw2[6], h2[6], pk_mul(lo2(b3), dxv));
      h2[7] = pk_fma(pw2[7], h2[7], pk_mul(hi2(b3), dxv));
    }
    #pragma unroll
    for (int j=0;j<4;j++)
      *(float4*)&Q[sbase + 4*j] = (float4){h2[2*j].x,h2[2*j].y,h2[2*j+1].x,h2[2*j+1].y};
  } else {
    float A[16];
    #pragma unroll
    for (int j=0;j<4;j++)
      *(float4*)&A[4*j] = *(const float4*)&AEX[(size_t)dir*4096 + d*16 + j*4];
    float h[16];
    #pragma unroll
    for (int n=0;n<16;n++) h[n]=0.f;
    for (int p=0;p<CH;p++){
      const float* rw = &dblS[p*24];
      float4 t0 = *(const float4*)&rw[0], t1 = *(const float4*)&rw[4];
      float a0 = bbt + t0.x*wv2[0].x+t0.y*wv2[0].y+t0.z*wv2[1].x+t0.w*wv2[1].y
                     + t1.x*wv2[2].x+t1.y*wv2[2].y+t1.z*wv2[3].x+t1.w*wv2[3].y;
      float dtv = (a0>20.f)? a0 : __logf(1.f+__expf(a0));
      dtp[(size_t)p*512] = f2h(dtv);
      float xiv = bs2f(xip[(size_t)p*256]);
      float dx = dtv*xiv;
      sdt += dtv;
      float bc[16];
      *(float4*)&bc[0]  = *(const float4*)&rw[8];
      *(float4*)&bc[4]  = *(const float4*)&rw[12];
      *(float4*)&bc[8]  = *(const float4*)&rw[16];
      *(float4*)&bc[12] = *(const float4*)&rw[20];
      #pragma unroll
      for (int n=0;n<16;n++){
        float a = __expf(dtv*A[n]);
        h[n] = a*h[n] + bc[n]*dx;
      }
    }
    #pragma unroll
    for (int j=0;j<4;j++)
      *(float4*)&Q[sbase + 4*j] = (float4){h[4*j],h[4*j+1],h[4*j+2],h[4*j+3]};
  }
  SD[(((size_t)dir*Bsz + b)*NC + c)*256 + d] = sdt;
}

// ---------------------------------------------------------------------------
// Phase 2a: group-local combine, PARALLEL over NG=16 chunk-groups.
// In-place: Q[c] -> group-local chunk-START state; SD[c] -> group-local
// prefix-sdt. Emits group aggregates SDG (total sdt) and QG (group-end H).
// ---------------------------------------------------------------------------
__global__ __launch_bounds__(64) void k_scan2a(float* __restrict__ SD, float* __restrict__ Q,
                        float* __restrict__ SDG, float* __restrict__ QG,
                        const float* __restrict__ AEX){
  int zb = blockIdx.z;                 // dir*Bsz + b
  int dir = zb >> 2;
  int g  = blockIdx.y;                 // group 0..15
  int t  = blockIdx.x*64 + threadIdx.x;  // 0..1023 state-quads
  int dn4 = t*4;
  int d = dn4 >> 4;
  float4 A4 = *(const float4*)&AEX[(size_t)dir*4096 + dn4];
  float* sd = SD + (((size_t)zb*NC) + (size_t)g*(NC/NG))*256 + d;
  float* q  = Q + (size_t)zb*NC*4096 + (size_t)g*(NC/NG)*4096 + dn4;
  float4 H = {0.f,0.f,0.f,0.f};
  float S = 0.f;
  #pragma unroll
  for (int c2=0; c2<NC/NG; c2++){
    float s_c = sd[(size_t)c2*256];
    float4 q_c = *(const float4*)(q + (size_t)c2*4096);
    sd[(size_t)c2*256] = S;
    *(float4*)(q + (size_t)c2*4096) = H;
    float4 p;
    p.x = __expf(A4.x*s_c); p.y = __expf(A4.y*s_c);
    p.z = __expf(A4.z*s_c); p.w = __expf(A4.w*s_c);
    H.x = p.x*H.x + q_c.x; H.y = p.y*H.y + q_c.y;
    H.z = p.z*H.z + q_c.z; H.w = p.w*H.w + q_c.w;
    S += s_c;
  }
  SDG[((size_t)zb*NG + g)*256 + d] = S;
  *(float4*)&QG[((size_t)zb*NG + g)*4096 + dn4] = H;
}

// Phase 2b: serial combine of NG=16 group aggregates. QG[g] is overwritten
// with the group-START absolute state.
__global__ __launch_bounds__(64) void k_scan2b(const float* __restrict__ SDG, float* __restrict__ QG,
                        const float* __restrict__ AEX){
  int b = blockIdx.y, dir = blockIdx.z;
  int zb = dir*Bsz + b;
  int t = blockIdx.x*64 + threadIdx.x;   // 0..1023
  int dn4 = t*4;
  int d = dn4 >> 4;
  float4 A4 = *(const float4*)&AEX[(size_t)dir*4096 + dn4];
  const float* sg = SDG + (size_t)zb*NG*256 + d;
  float* qg = QG + (size_t)zb*NG*4096 + dn4;
  float4 H = {0.f,0.f,0.f,0.f};
  #pragma unroll
  for (int g=0; g<NG; g++){
    float s = sg[(size_t)g*256];
    float4 qe = *(const float4*)(qg + (size_t)g*4096);
    *(float4*)(qg + (size_t)g*4096) = H;
    float4 p;
    p.x = __expf(A4.x*s); p.y = __expf(A4.y*s);
    p.z = __expf(A4.z*s); p.w = __expf(A4.w*s);
    H.x = p.x*H.x + qe.x; H.y = p.y*H.y + qe.y;
    H.z = p.z*H.z + qe.z; H.w = p.w*H.w + qe.w;
  }
}

// ---------------------------------------------------------------------------
// Phase 3: re-scan from start states. Chunk-start state reconstructed as
//   H_start(c) = exp(A*SD_prefix(c)) o QG[group(c)] + Q_local(c)   (exact).
// dtv loaded from the fp16 side-channel (no dt-chain recompute). Gating by
// silu(z) applied here (VALU-bound kernel absorbs it).
// ---------------------------------------------------------------------------
__global__ __launch_bounds__(256) void k_scan3(const float* __restrict__ dbl,
                       unsigned short* xiy, const float* __restrict__ AEX,
                       const float* __restrict__ A0C, const float* __restrict__ CHNf,
                       const float* __restrict__ Dpw, const float* __restrict__ Hs,
                       const float* __restrict__ SDp, const float* __restrict__ QG,
                       const unsigned short* __restrict__ xz){
  __shared__ float dblS[CH*32];
  int b = blockIdx.y, c = blockIdx.x, dir = blockIdx.z;
  int d = threadIdx.x;
  const float* dblP = dbl + (size_t)dir*Bsz*Ll*40;
  unsigned short* xiP = xiy + (size_t)dir*Bsz*Ll*256;
  const unsigned short* xzP = xz + (size_t)dir*Bsz*Ll*512;
  size_t base = (size_t)b*Ll + (size_t)c*CH;
  if (d < CH*8){
    int p = d>>3, j = d&7;
    *(float4*)&dblS[p*32 + j*4] = *(const float4*)&dblP[(base+p)*40 + 8 + j*4];
  }
  float A0 = A0C[dir*256 + d];
  bool chain = CHNf[dir*256 + d] != 0.f;
  float Dp = Dpw[dir*256 + d];
  int zb = dir*Bsz + b;
  size_t sbase = (size_t)zb*NC*4096 + (size_t)c*4096 + (size_t)d*16;
  float sdtp = SDp[(((size_t)zb)*NC + c)*256 + d];
  size_t gbase = ((size_t)zb*NG + (c >> 4))*4096 + (size_t)d*16;
  __syncthreads();
  unsigned short* xip = xiP + base*256 + d;
  const unsigned short* dtp = xzP + base*512 + d;        // fp16 dtv
  const unsigned short* zp  = xzP + base*512 + 256 + d;  // bf16 z
  if (chain){
    float xv[CH], zv[CH], dv[CH];
    #pragma unroll
    for (int p=0;p<CH;p++) xv[p] = bs2f(xip[(size_t)p*256]);
    #pragma unroll
    for (int p=0;p<CH;p++) zv[p] = bs2f(zp[(size_t)p*512]);
    #pragma unroll
    for (int p=0;p<CH;p++) dv[p] = h2f(dtp[(size_t)p*512]);
    // reconstruct chunk-start state: h = pw(exp(A0*sdtp)) * QG + Qlocal
    f32x2 h2[8];
    {
      float eg = __expf(A0*sdtp);
      f32x2 pg[8];
      POWTREE2(eg, pg);
      #pragma unroll
      for (int j=0;j<4;j++){
        float4 h4 = *(const float4*)&Hs[sbase + 4*j];
        float4 g4 = *(const float4*)&QG[gbase + 4*j];
        h2[2*j]   = pk_fma(pg[2*j],   (f32x2){g4.x,g4.y}, (f32x2){h4.x,h4.y});
        h2[2*j+1] = pk_fma(pg[2*j+1], (f32x2){g4.z,g4.w}, (f32x2){h4.z,h4.w});
      }
    }
    #pragma unroll
    for (int p=0;p<CH;p++){
      const float* rw = &dblS[p*32];
      float dtv = dv[p];
      float e1 = __expf(dtv*A0);
      float dx = dtv*xv[p];
      f32x2 pw2[8];
      POWTREE2(e1, pw2);
      f32x2 dxv = (f32x2){dx,dx};
      f32x4 b0 = *(const f32x4*)&rw[0];
      f32x4 b1 = *(const f32x4*)&rw[4];
      f32x4 b2 = *(const f32x4*)&rw[8];
      f32x4 b3 = *(const f32x4*)&rw[12];
      f32x4 c0 = *(const f32x4*)&rw[16];
      f32x4 c1 = *(const f32x4*)&rw[20];
      f32x4 c2 = *(const f32x4*)&rw[24];
      f32x4 c3 = *(const f32x4*)&rw[28];
      f32x2 ya;
      h2[0] = pk_fma(pw2[0], h2[0], pk_mul(lo2(b0), dxv));
      ya = pk_mul(h2[0], lo2(c0));
      h2[1] = pk_fma(pw2[1], h2[1], pk_mul(hi2(b0), dxv));
      ya = pk_fma(h2[1], hi2(c0), ya);
      h2[2] = pk_fma(pw2[2], h2[2], pk_mul(lo2(b1), dxv));
      ya = pk_fma(h2[2], lo2(c1), ya);
      h2[3] = pk_fma(pw2[3], h2[3], pk_mul(hi2(b1), dxv));
      ya = pk_fma(h2[3], hi2(c1), ya);
      h2[4] = pk_fma(pw2[4], h2[4], pk_mul(lo2(b2), dxv));
      ya = pk_fma(h2[4], lo2(c2), ya);
      h2[5] = pk_fma(pw2[5], h2[5], pk_mul(hi2(b2), dxv));
      ya = pk_fma(h2[5], hi2(c2), ya);
      h2[6] = pk_fma(pw2[6], h2[6], pk_mul(lo2(b3), dxv));
      ya = pk_fma(h2[6], lo2(c3), ya);
      h2[7] = pk_fma(pw2[7], h2[7], pk_mul(hi2(b3), dxv));
      ya = pk_fma(h2[7], hi2(c3), ya);
      float acc = ya.x + ya.y;
      float z = zv[p];
      float g = z*__builtin_amdgcn_rcpf(1.f+__expf(-z));
      xip[(size_t)p*256] = f2bs((acc + Dp*xv[p])*g);
    }
  } else {
    float A[16];
    #pragma unroll
    for (int j=0;j<4;j++)
      *(float4*)&A[4*j] = *(const float4*)&AEX[(size_t)dir*4096 + d*16 + j*4];
    float h[16];
    #pragma unroll
    for (int j=0;j<4;j++){
      float4 h4 = *(const float4*)&Hs[sbase + 4*j];
      float4 g4 = *(const float4*)&QG[gbase + 4*j];
      h[4*j]   = __expf(A[4*j]*sdtp)*g4.x   + h4.x;
      h[4*j+1] = __expf(A[4*j+1]*sdtp)*g4.y + h4.y;
      h[4*j+2] = __expf(A[4*j+2]*sdtp)*g4.z + h4.z;
      h[4*j+3] = __expf(A[4*j+3]*sdtp)*g4.w + h4.w;
    }
    for (int p=0;p<CH;p++){
      const float* rw = &dblS[p*32];
      float dtv = h2f(dtp[(size_t)p*512]);
      float xiv = bs2f(xip[(size_t)p*256]);
      float dx = dtv*xiv;
      float bc[16], cc[16];
      *(float4*)&bc[0]  = *(const float4*)&rw[0];
      *(float4*)&bc[4]  = *(const float4*)&rw[4];
      *(float4*)&bc[8]  = *(const float4*)&rw[8];
      *(float4*)&bc[12] = *(const float4*)&rw[12];
      *(float4*)&cc[0]  = *(const float4*)&rw[16];
      *(float4*)&cc[4]  = *(const float4*)&rw[20];
      *(float4*)&cc[8]  = *(const float4*)&rw[24];
      *(float4*)&cc[12] = *(const float4*)&rw[28];
      float acc = 0.f;
      #pragma unroll
      for (int n=0;n<16;n++){
        float a = __expf(dtv*A[n]);
        h[n] = a*h[n] + bc[n]*dx;
        acc += h[n]*cc[n];
      }
      float z = bs2f(zp[(size_t)p*512]);
      float g = z*__builtin_amdgcn_rcpf(1.f+__expf(-z));
      xip[(size_t)p*256] = f2bs((acc + Dp*xiv)*g);
    }
  }
}

// final transpose (B,L,128) fp32 -> (B,128,L) fp32
__global__ __launch_bounds__(256) void k_final(const float* __restrict__ hres, float* __restrict__ out){
  __shared__ float tile[64*129];
  int b = blockIdx.y, l0 = blockIdx.x*64;
  int tid = threadIdx.x;
  for (int q=0;q<32;q++){
    int idx = q*256 + tid;
    int l = idx >> 7, c = idx & 127;
    tile[l*129 + c] = hres[((size_t)b*Ll + l0 + l)*128 + c];
  }
  __syncthreads();
  int lo = tid & 63; int cbase = tid >> 6;
  for (int q=0;q<32;q++){
    int c = cbase + q*4;
    out[((size_t)b*128 + c)*Ll + l0 + lo] = tile[lo*129 + c];
  }
}

extern "C" void kernel_launch(void* const* d_in, const int* in_sizes, int n_in,
                              void* d_out, int out_size, void* d_ws, size_t ws_size,
                              hipStream_t stream){
  const float* x      = (const float*)d_in[0];
  const float* skip   = (const float*)d_in[1];
  const float* up_w   = (const float*)d_in[2];
  const float* up_b   = (const float*)d_in[3];
  const float* fus_w  = (const float*)d_in[4];
  const float* fus_b  = (const float*)d_in[5];
  const float* gn_w   = (const float*)d_in[6];
  const float* gn_b   = (const float*)d_in[7];
  const float* pa     = (const float*)d_in[8];
  const float* ln_w   = (const float*)d_in[9];
  const float* ln_b   = (const float*)d_in[10];
  const float* in_w   = (const float*)d_in[11];
  const float* conv_w = (const float*)d_in[12];
  const float* conv_b = (const float*)d_in[13];
  const float* xproj_w= (const float*)d_in[14];
  const float* dtproj_w=(const float*)d_in[15];
  const float* dtproj_b=(const float*)d_in[16];
  const float* A_log  = (const float*)d_in[17];
  const float* Dp     = (const float*)d_in[18];
  const float* out_w  = (const float*)d_in[19];

  // Workspace (~104 MiB). U1 holds XT+SKT (preamble) then SQ (loop).
  // SD and QG alias XNB exactly; SDG is a small fresh allocation. dtv (fp16)
  // lives in the DEAD x-half of XZB2 between scan1 and scan3.
  float* w = (float*)d_ws;
  size_t off=0;
  float* B2 = w+off; off += 128;
  float* GST= w+off; off += 16;
  off = (off+3)&~(size_t)3;
  float* HR = w+off; off += (size_t)Bsz*Ll*128;
  float* DBL2= w+off; off += 2*(size_t)Bsz*Ll*40;
  unsigned short* XNB = (unsigned short*)(w+off); off += (size_t)Bsz*Ll*128/2;
  unsigned short* XZB2= (unsigned short*)(w+off); off += 2*(size_t)Bsz*Ll*512/2;
  unsigned short* IWB = (unsigned short*)(w+off); off += 2*2*512*128/2;
  unsigned short* OWB = (unsigned short*)(w+off); off += 2*2*128*256/2;
  unsigned short* WXB = (unsigned short*)(w+off); off += 2*2*64*256/2;
  unsigned short* WEb = (unsigned short*)(w+off); off += 768*128/2;
  unsigned short* WOb = (unsigned short*)(w+off); off += 512*128/2;
  unsigned short* FWSb= (unsigned short*)(w+off); off += 128*128/2;
  float* AEXb = w+off; off += 4*4096;
  float* A0Cb = w+off; off += 4*256;
  float* CHNb = w+off; off += 4*256;
  float* SDGb = w+off; off += (size_t)2*Bsz*NG*256;   // 32K floats
  size_t planeS = (size_t)Bsz*NC*4096;       // 4,194,304 @ NC=256
  float* U1 = w+off; off += 2*planeS;        // SQ (and preamble XT/SKT)
  unsigned short* XT  = (unsigned short*)U1;
  unsigned short* SKT = (unsigned short*)(U1 + 1049604);
  float* SQ = U1;
  float* SD = (float*)XNB;                   // 524,288 floats
  float* QG = SD + 524288;                   // 524,288 floats (2*Bsz*NG*4096)
  float* U2 = w+off; off += 2*(size_t)Bsz*Ll*128;
  float* H0 = U2;
  unsigned short* XIB2 = (unsigned short*)U2;

  hipMemsetAsync(GST, 0, 16*sizeof(float), stream);
  k_cvt2<<<(2*2*512*128 + 2*2*128*256 + 255)/256,256,0,stream>>>(in_w, out_w, IWB, OWB,
                                                                 2*2*512*128, 2*2*128*256);
  k_prepx<<<dim3(64,4),256,0,stream>>>(xproj_w, WXB);
  k_prepA<<<4,256,0,stream>>>(A_log, AEXb, A0Cb, CHNb);
  k_compose<<<256,128,0,stream>>>(up_w, fus_w, fus_b, up_b, WEb, WOb, FWSb, B2);
  k_tx<<<dim3(Tt/64, 4, Bsz),256,0,stream>>>(x, XT);
  k_ts<<<dim3(Ll/64, 2, Bsz),256,0,stream>>>(skip, SKT);
  k_up<<<dim3(32, 2, Bsz),256,0,stream>>>(XT, SKT, WEb, WOb, FWSb, B2, H0, GST);
  k_gnln<<<Bsz*Ll/4,256,0,stream>>>(H0, gn_w, gn_b, pa, GST, ln_w, ln_b, HR, XNB);
  for (int i=0;i<2;i++){
    k_gemm_in<<<dim3(128,4,2),256,0,stream>>>(XNB, IWB + (size_t)(i*2)*512*128, XZB2);
    k_xproj3<<<dim3(Bsz*Ll/64,2),256,0,stream>>>(XZB2, WXB + (size_t)(i*2)*64*256,
                                                 conv_w + (i*2)*1024, conv_b + (i*2)*256,
                                                 XIB2, DBL2);
    k_scan1<<<dim3(NC,Bsz,2),256,0,stream>>>(DBL2, XIB2, XZB2, AEXb + (size_t)(i*2)*4096,
                                             A0Cb + (i*2)*256, CHNb + (i*2)*256,
                                             dtproj_w + (i*2)*2048, dtproj_b + (i*2)*256, SD, SQ);
    k_scan2a<<<dim3(16,NG,2*Bsz),64,0,stream>>>(SD, SQ, SDGb, QG, AEXb + (size_t)(i*2)*4096);
    k_scan2b<<<dim3(16,Bsz,2),64,0,stream>>>(SDGb, QG, AEXb + (size_t)(i*2)*4096);
    k_scan3<<<dim3(NC,Bsz,2),256,0,stream>>>(DBL2, XIB2, AEXb + (size_t)(i*2)*4096,
                                             A0Cb + (i*2)*256, CHNb + (i*2)*256,
                                             Dp + (i*2)*256, SQ, SD, QG, XZB2);
    if (i==0)
      k_gemm_out_t<1><<<256,256,0,stream>>>(XIB2, OWB + 0, HR, ln_w + 128, ln_b + 128, XNB);
    else
      k_gemm_out_t<0><<<256,256,0,stream>>>(XIB2, OWB + (size_t)2*128*256, HR,
                                            (const float*)nullptr, (const float*)nullptr,
                                            (unsigned short*)nullptr);
  }
  k_final<<<dim3(Ll/64,Bsz),256,0,stream>>>(HR, (float*)d_out);
}